// Round 11
// baseline (510.977 us; speedup 1.0000x reference)
//
#include <hip/hip_runtime.h>
#include <hip/hip_bf16.h>

// ---------------------------------------------------------------------------
// GAT (2 GATConv + 5-layer MLP), MI355X.
// R16: gemm/mlp staging -> global_load_lds(16B) + both-sides XOR swizzle.
// R17-R21: elimination matrix -> agg latency-chain bound. R20 structure
//     (2 nodes/block, 384 thr, direct exp, 8-deep batch, barrier-free).
// R23 (WIN 495.7): int8 rowmax-scaled gather both layers, absmax 7.63e-6.
// R24 (NET-NEGATIVE 507.9): edge_w precompute helped agg (93.5->84.8) but
//     cost +30 us in its own kernels. Reverted to R23 in-agg form.
// R25: single-term bf16 gemms via EXACT logits decoupling:
//     el = (X·W)·a == X·(W·a). u-vectors (W·a, 6x128/layer) computed in
//     prep; layer-1 el/er from fp32 in_feat in tiny node_el kernel (exact);
//     layer-2 el/er fused into agg1 epilogue from fp32 h2 in LDS (exact).
//     Gemms now only feed the int8 quantizer (0.61% RMS) -> bf16 single-term
//     value error 0.16% is negligible in quadrature. MFMA/gemm /3, staging
//     planes 4->2, LDS 32->16KB. prep drops P1-lo + w1/w2-lo transposes;
//     agg1 writes only P2-hi. Predicted absmax ~8e-6.
// ---------------------------------------------------------------------------

typedef __attribute__((ext_vector_type(8))) short short8;   // 8 bf16 = 4 VGPR
typedef __attribute__((ext_vector_type(4))) float float4v;  // MFMA C/D

__device__ inline short f2bf(float x) {
    union { float f; unsigned u; } v; v.f = x;
    unsigned r = v.u + 0x7FFFu + ((v.u >> 16) & 1u);   // RNE
    return (short)(r >> 16);
}
__device__ inline float bf2f(short b) {
    union { float f; unsigned u; } v;
    v.u = ((unsigned)(unsigned short)b) << 16;
    return v.f;
}
__device__ inline short8 zero8() { short8 z = {0,0,0,0,0,0,0,0}; return z; }

// async global->LDS, 16 B per lane (dest = wave-uniform base + lane*16)
__device__ __forceinline__ void gl_lds16(const short* g, short* l) {
    __builtin_amdgcn_global_load_lds(
        (const __attribute__((address_space(1))) void*)g,
        (__attribute__((address_space(3))) void*)l,
        16, 0, 0);
}

// XOR swizzle for 16B slots within a 64B row (8-way -> 2-way, free per m136).
#define SW(r) ((((r) >> 2) ^ (r)) & 3)

#define BM 128
#define BN 128
#define BK 32
#define MSTR 136   // act row stride in shorts (272 B = 17x16B, breaks pow2)
#define MROWS 64   // mlp_fused rows per block

// ---------------------------------------------------------------------------
// Fused prep: [0,cb) conv (hi only) | [cb,cb+wb) weight transpose |
// [cb+wb] u-vectors (W·a per layer) | rest hist.
__global__ void prep_kernel(
    const float* __restrict__ in_feat, short* __restrict__ P1h,
    int n4, int cb, int wb,
    const int* __restrict__ dst, int* __restrict__ cnt, int E,
    const float* __restrict__ w1, const float* __restrict__ w2,
    const float* __restrict__ m1, const float* __restrict__ m2,
    const float* __restrict__ m3, const float* __restrict__ m4,
    const float* __restrict__ w5,
    short* __restrict__ w1h, short* __restrict__ w2h,
    short* __restrict__ m1h, short* __restrict__ m1l,
    short* __restrict__ m2h, short* __restrict__ m2l,
    short* __restrict__ m3h, short* __restrict__ m3l,
    short* __restrict__ m4h, short* __restrict__ m4l,
    short* __restrict__ w5h, short* __restrict__ w5l,
    const float* __restrict__ al1, const float* __restrict__ ar1,
    const float* __restrict__ al2, const float* __restrict__ ar2,
    float* __restrict__ u1, float* __restrict__ u2)
{
    int blk = blockIdx.x;
    if (blk < cb) {
        int i = blk * 256 + threadIdx.x;
        if (i >= n4) return;
        float4 v = *(const float4*)(in_feat + (size_t)i * 4);
        float xs[4] = {v.x, v.y, v.z, v.w};
        short hs[4];
        #pragma unroll
        for (int j = 0; j < 4; ++j) hs[j] = f2bf(xs[j]);
        *(uint2*)(P1h + (size_t)i * 4) = *(uint2*)hs;
    } else if (blk < cb + wb) {
        int j = (blk - cb) * 256 + threadIdx.x;
        const float* src; short* th; short* tl; int Nc, base;
        if      (j < 49152)  { src = w1; th = w1h; tl = nullptr; Nc = 384; base = 0; }
        else if (j < 98304)  { src = w2; th = w2h; tl = nullptr; Nc = 384; base = 49152; }
        else if (j < 114688) { src = m1; th = m1h; tl = m1l; Nc = 128; base = 98304; }
        else if (j < 131072) { src = m2; th = m2h; tl = m2l; Nc = 128; base = 114688; }
        else if (j < 147456) { src = m3; th = m3h; tl = m3l; Nc = 128; base = 131072; }
        else if (j < 163840) { src = m4; th = m4h; tl = m4l; Nc = 128; base = 147456; }
        else if (j < 164608) { src = w5; th = w5h; tl = w5l; Nc = 6;   base = 163840; }
        else return;
        int i = j - base;
        int k = i / Nc, c = i - k * Nc;
        float v = src[i];
        short h = f2bf(v);
        th[(size_t)c * 128 + k] = h;
        if (tl) tl[(size_t)c * 128 + k] = f2bf(v - bf2f(h));
    } else if (blk == cb + wb) {
        // u-vectors: u[(h*2+s)*128 + k] = sum_f W[k*384 + h*128 + f] * a[h*128+f]
        int t = threadIdx.x;
        const float* W  = (t < 128) ? w1 : w2;
        const float* av = (t < 128) ? al1 : al2;
        const float* rv = (t < 128) ? ar1 : ar2;
        float* u = (t < 128) ? u1 : u2;
        int k = t & 127;
        #pragma unroll
        for (int h = 0; h < 3; ++h) {
            float sl = 0.f, sr = 0.f;
            for (int f = 0; f < 128; ++f) {
                float wv = W[(size_t)k * 384 + h * 128 + f];
                sl += wv * av[h * 128 + f];
                sr += wv * rv[h * 128 + f];
            }
            u[(h * 2 + 0) * 128 + k] = sl;
            u[(h * 2 + 1) * 128 + k] = sr;
        }
    } else {
        int e = (blk - cb - wb - 1) * 256 + threadIdx.x;
        if (e < E) atomicAdd(&cnt[dst[e]], 1);
    }
}

// ---------------------------------------------------------------------------
// node_el: EXACT layer-1 logits from fp32 X. el/er[n,h] = X[n,:]·u1[h,side].
// 4 nodes per 256-thr block (1 wave per node).
__global__ __launch_bounds__(256) void node_el(
    const float* __restrict__ X, const float* __restrict__ u,
    float* __restrict__ els, float* __restrict__ er, int N)
{
    int n = blockIdx.x * 4 + (threadIdx.x >> 6);
    int l = threadIdx.x & 63;
    if (n >= N) return;
    float2 x = *(const float2*)(X + (size_t)n * 128 + 2 * l);
    float a[6];
    #pragma unroll
    for (int v = 0; v < 6; ++v)
        a[v] = x.x * u[v * 128 + 2 * l] + x.y * u[v * 128 + 2 * l + 1];
    #pragma unroll
    for (int msk = 1; msk < 64; msk <<= 1)
        #pragma unroll
        for (int v = 0; v < 6; ++v)
            a[v] += __shfl_xor(a[v], msk);
    if (l == 0) {
        #pragma unroll
        for (int h = 0; h < 3; ++h) {
            els[(size_t)(n * 3 + h) * 2] = a[h * 2];
            er[n * 3 + h] = a[h * 2 + 1];
        }
    }
}

// ---------------------------------------------------------------------------
// GEMM (GAT layers): single-term bf16 (values only feed int8 quantizer;
// logits computed exactly elsewhere). One head per col-block (blockIdx.x).
// Outputs: int8 rowmax-quantized Cq + per-(row,head) scale -> els slot 1.
__global__ __launch_bounds__(256) void gemm_mfma(
    const short* __restrict__ Ahi, const short* __restrict__ Bth,
    unsigned char* __restrict__ Cq, float* __restrict__ els,
    int M, int Nc)
{
    __shared__ short Ah[BM * BK], Bh[BN * BK];

    int tid = threadIdx.x, lane = tid & 63, wave = tid >> 6;
    int l15 = lane & 15, q = lane >> 4;
    int rowBase = blockIdx.y * BM, colBase = blockIdx.x * BN;

    float4v acc[2][8];
    #pragma unroll
    for (int mt = 0; mt < 2; ++mt)
        #pragma unroll
        for (int nt = 0; nt < 8; ++nt)
            acc[mt][nt] = (float4v){0.f, 0.f, 0.f, 0.f};

    for (int k0 = 0; k0 < 128; k0 += BK) {
        #pragma unroll
        for (int i = 0; i < 2; ++i) {
            int cid = tid + i * 256;             // wave-uniform base + lane
            int r = cid >> 2, sub = cid & 3;
            int gs = (sub ^ SW(r)) * 8;
            gl_lds16(Ahi + (size_t)(rowBase + r) * 128 + k0 + gs, Ah + cid * 8);
            gl_lds16(Bth + (size_t)(colBase + r) * 128 + k0 + gs, Bh + cid * 8);
        }
        __syncthreads();

        short8 aH[2];
        #pragma unroll
        for (int mt = 0; mt < 2; ++mt) {
            int row = wave * 32 + mt * 16 + l15;
            int off = row * 32 + (q ^ SW(row)) * 8;
            aH[mt] = *(short8*)&Ah[off];
        }
        #pragma unroll
        for (int nt = 0; nt < 8; ++nt) {
            int row = nt * 16 + l15;
            int off = row * 32 + (q ^ SW(row)) * 8;
            short8 bH = *(short8*)&Bh[off];
            #pragma unroll
            for (int mt = 0; mt < 2; ++mt)
                acc[mt][nt] = __builtin_amdgcn_mfma_f32_16x16x32_bf16(aH[mt], bH, acc[mt][nt], 0, 0, 0);
        }
        __syncthreads();
    }

    // ---- int8 rowmax quantization: scale = rowmax/127 per (row, head)
    #pragma unroll
    for (int mt = 0; mt < 2; ++mt) {
        #pragma unroll
        for (int i = 0; i < 4; ++i) {
            float rm = 0.f;
            #pragma unroll
            for (int nt = 0; nt < 8; ++nt)
                rm = fmaxf(rm, fabsf(acc[mt][nt][i]));
            #pragma unroll
            for (int mask = 1; mask < 16; mask <<= 1)
                rm = fmaxf(rm, __shfl_xor(rm, mask));
            int r = rowBase + wave * 32 + mt * 16 + q * 4 + i;
            float inv = 127.f / fmaxf(rm, 1e-30f);
            if (l15 == 0 && r < M)
                els[(size_t)(r * 3 + blockIdx.x) * 2 + 1] = rm * (1.f / 127.f);
            #pragma unroll
            for (int nt = 0; nt < 8; ++nt) {
                int c = colBase + nt * 16 + l15;
                int qi = (int)rintf(acc[mt][nt][i] * inv);
                int qn = __shfl_xor(qi, 1);        // neighbor col c^1
                if (!(l15 & 1) && r < M && c < Nc) {
                    unsigned short pk = (unsigned short)((qi & 0xFF) | ((qn & 0xFF) << 8));
                    *(unsigned short*)(Cq + (size_t)r * Nc + c) = pk;
                }
            }
        }
    }
}

// ---------------------------------------------------------------------------
// Fused MLP head: 4x (128->128, bias, lrelu) + (128->6, bias) in one kernel.
__global__ __launch_bounds__(256) void mlp_fused(
    const short* __restrict__ Ph, const short* __restrict__ Pl,
    const short* __restrict__ w1h, const short* __restrict__ w1l,
    const short* __restrict__ w2h, const short* __restrict__ w2l,
    const short* __restrict__ w3h, const short* __restrict__ w3l,
    const short* __restrict__ w4h, const short* __restrict__ w4l,
    const short* __restrict__ w5h, const short* __restrict__ w5l,
    const float* __restrict__ b1, const float* __restrict__ b2,
    const float* __restrict__ b3, const float* __restrict__ b4,
    const float* __restrict__ b5,
    float* __restrict__ out, int M)
{
    __shared__ short AH[MROWS * MSTR], AL[MROWS * MSTR];
    __shared__ short WH[128 * BK], WL[128 * BK];

    int tid = threadIdx.x, lane = tid & 63, wave = tid >> 6;
    int l15 = lane & 15, q = lane >> 4;
    int rowBase = blockIdx.x * MROWS;

    #pragma unroll
    for (int s = 0; s < 4; ++s) {
        int idx = tid + s * 256;
        int r = idx >> 4, kq = (idx & 15) * 8;
        int gr = rowBase + r;
        short8 vh = zero8(), vl = zero8();
        if (gr < M) {
            vh = *(const short8*)(Ph + (size_t)gr * 128 + kq);
            vl = *(const short8*)(Pl + (size_t)gr * 128 + kq);
        }
        *(short8*)&AH[r * MSTR + kq] = vh;
        *(short8*)&AL[r * MSTR + kq] = vl;
    }

    const short* Whs[4] = {w1h, w2h, w3h, w4h};
    const short* Wls[4] = {w1l, w2l, w3l, w4l};
    const float* Bss[4] = {b1, b2, b3, b4};

    #pragma unroll
    for (int L = 0; L < 4; ++L) {
        float4v acc[8];
        #pragma unroll
        for (int nt = 0; nt < 8; ++nt)
            acc[nt] = (float4v){0.f, 0.f, 0.f, 0.f};

        for (int k0 = 0; k0 < 128; k0 += BK) {
            #pragma unroll
            for (int i = 0; i < 4; ++i) {          // i<2: hi plane, i>=2: lo
                int c2 = tid + (i & 1) * 256;       // 0..511
                int r = c2 >> 2, sub = c2 & 3;
                int gs = (sub ^ SW(r)) * 8;
                if (i < 2) gl_lds16(Whs[L] + (size_t)r * 128 + k0 + gs, WH + c2 * 8);
                else       gl_lds16(Wls[L] + (size_t)r * 128 + k0 + gs, WL + c2 * 8);
            }
            __syncthreads();
            int offa = (wave * 16 + l15) * MSTR + k0 + q * 8;
            short8 aH  = *(short8*)&AH[offa];
            short8 aL2 = *(short8*)&AL[offa];
            #pragma unroll
            for (int nt = 0; nt < 8; ++nt) {
                int row = nt * 16 + l15;
                int off = row * 32 + (q ^ SW(row)) * 8;
                short8 bH = *(short8*)&WH[off];
                short8 bL = *(short8*)&WL[off];
                acc[nt] = __builtin_amdgcn_mfma_f32_16x16x32_bf16(aH, bH, acc[nt], 0, 0, 0);
                acc[nt] = __builtin_amdgcn_mfma_f32_16x16x32_bf16(aH, bL, acc[nt], 0, 0, 0);
                acc[nt] = __builtin_amdgcn_mfma_f32_16x16x32_bf16(aL2, bH, acc[nt], 0, 0, 0);
            }
            __syncthreads();
        }
        #pragma unroll
        for (int nt = 0; nt < 8; ++nt) {
            int c = nt * 16 + l15;
            float bv = Bss[L][c];
            #pragma unroll
            for (int i = 0; i < 4; ++i) {
                int r = wave * 16 + q * 4 + i;
                float v = acc[nt][i] + bv;
                v = (v < 0.f) ? 0.01f * v : v;
                short hh = f2bf(v);
                AH[r * MSTR + c] = hh;
                AL[r * MSTR + c] = f2bf(v - bf2f(hh));
            }
        }
        __syncthreads();
    }

    float4v acc5 = (float4v){0.f, 0.f, 0.f, 0.f};
    for (int k0 = 0; k0 < 128; k0 += BK) {
        if (tid < 128) {
            int plane = tid >> 6, rem = tid & 63;
            int c = rem >> 2, sub = rem & 3;
            short8 v = zero8();
            if (c < 6)
                v = *(const short8*)((plane ? w5l : w5h) + (size_t)c * 128 + k0 + sub * 8);
            *(short8*)&((plane ? WL : WH)[c * 32 + (sub ^ SW(c)) * 8]) = v;
        }
        __syncthreads();
        int offa = (wave * 16 + l15) * MSTR + k0 + q * 8;
        short8 aH  = *(short8*)&AH[offa];
        short8 aL2 = *(short8*)&AL[offa];
        int offb = l15 * 32 + (q ^ SW(l15)) * 8;
        short8 bH = *(short8*)&WH[offb];
        short8 bL = *(short8*)&WL[offb];
        acc5 = __builtin_amdgcn_mfma_f32_16x16x32_bf16(aH, bH, acc5, 0, 0, 0);
        acc5 = __builtin_amdgcn_mfma_f32_16x16x32_bf16(aH, bL, acc5, 0, 0, 0);
        acc5 = __builtin_amdgcn_mfma_f32_16x16x32_bf16(aL2, bH, acc5, 0, 0, 0);
        __syncthreads();
    }
    if (l15 < 6) {
        float bv = b5[l15];
        #pragma unroll
        for (int i = 0; i < 4; ++i) {
            int r = rowBase + wave * 16 + q * 4 + i;
            if (r < M) out[(size_t)r * 6 + l15] = acc5[i] + bv;
        }
    }
}

// ---------------------------------------------------------------------------
// CSR build (hist lives in prep_kernel)
__global__ __launch_bounds__(1024) void scan_block(const int* __restrict__ cnt,
                                                   int* __restrict__ off,
                                                   int* __restrict__ bsum, int n)
{
    __shared__ int tmp[1024];
    int tid = threadIdx.x;
    int i = blockIdx.x * 1024 + tid;
    int v = (i < n) ? cnt[i] : 0;
    tmp[tid] = v;
    __syncthreads();
    for (int s = 1; s < 1024; s <<= 1) {
        int t = (tid >= s) ? tmp[tid - s] : 0;
        __syncthreads();
        tmp[tid] += t;
        __syncthreads();
    }
    if (i < n) off[i] = tmp[tid] - v;
    if (tid == 1023) bsum[blockIdx.x] = tmp[1023];
}

__global__ void scan_add2(int* __restrict__ off, const int* __restrict__ bsum,
                          int n, int nb)
{
    __shared__ int pre[64];
    int tid = threadIdx.x;
    if (tid < 64) {
        int v = (tid < nb) ? bsum[tid] : 0;
        #pragma unroll
        for (int s = 1; s < 64; s <<= 1) {
            int t = __shfl_up(v, s);
            if (tid >= s) v += t;
        }
        pre[tid] = v;
    }
    __syncthreads();
    int i = blockIdx.x * blockDim.x + tid;
    if (i < n) {
        int chunk = i >> 10;
        off[i] += chunk ? pre[chunk - 1] : 0;
    }
    if (i == 0) off[n] = pre[nb - 1];
}

__global__ void scatter_kernel(const int* __restrict__ src, const int* __restrict__ dst,
                               const int* __restrict__ off, int* __restrict__ cnt,
                               int* __restrict__ csrc, int E)
{
    int e = blockIdx.x * blockDim.x + threadIdx.x;
    if (e < E) {
        int d = dst[e];
        int p = atomicSub(&cnt[d], 1) - 1;
        csrc[off[d] + p] = src[e];
    }
}

// ---------------------------------------------------------------------------
// Fused edge-softmax + weighted gather + bias + lrelu + head-mean.
// R23 form: in-loop {el,scale} float2 gather (L2-resident), int8 values,
// direct exp, 8-deep batch, barrier-free chunk loop, 2 nodes/block.
// R25: optional epilogue (u2v != null) emits EXACT layer-2 logits from the
// fp32 h2 values in LDS: el2/er2[n,h] = h2[n,:]·u2[h,side]. outL nullable.
__global__ __launch_bounds__(384) void agg_kernel(
    const unsigned char* __restrict__ h8, const float* __restrict__ els,
    const float* __restrict__ er, const int* __restrict__ off,
    const int* __restrict__ csrc, const float* __restrict__ bias,
    short* __restrict__ outH, short* __restrict__ outL,
    const float* __restrict__ u2v, float* __restrict__ els2,
    float* __restrict__ er2, int N)
{
    int tid = threadIdx.x;         // 0..383
    int u = tid >> 6;              // wave 0..5
    int nl = u / 3;                // node-local 0/1
    int head = u - nl * 3;         // 0..2
    int l = tid & 63;
    int n = blockIdx.x * 2 + nl;
    bool active = (n < N);

    __shared__ int   ssrcS[6][64];
    __shared__ float swS[6][64];
    __shared__ float smS[2][384];

    int beg = 0, deg = 0;
    float erv = 0.f;
    if (active) {
        beg = off[n];
        deg = off[n + 1] - beg;
        erv = er[n * 3 + head];
    }

    const unsigned char* hseg = h8 + head * 128 + l * 2;
    float ax = 0.f, ay = 0.f, denl = 0.f;

    for (int base = 0; base < deg; base += 64) {
        int cnt = min(64, deg - base);
        int s_l = 0; float w = 0.f, wS = 0.f;
        if (l < cnt) {
            s_l = csrc[beg + base + l];
            float2 e2 = *(const float2*)(els + (size_t)(s_l * 3 + head) * 2);
            float t = e2.x + erv;
            t = (t < 0.f) ? 0.2f * t : t;
            w = __expf(t);                 // direct exp: logits bounded
            wS = w * e2.y;                 // fold int8 scale into weight
        }
        denl += w;
        ssrcS[u][l] = s_l;                 // per-wave region: no barrier
        swS[u][l]   = wS;                  // (same-wave lgkmcnt ordering)
        for (int q0 = 0; q0 < cnt; q0 += 8) {
            int sA[8]; float wA[8]; unsigned vA[8];
            #pragma unroll
            for (int b = 0; b < 8; ++b) {
                int e = q0 + b;            // <= 63 always; pads have w=0,s=0
                sA[b] = ssrcS[u][e];
                wA[b] = swS[u][e];
            }
            #pragma unroll
            for (int b = 0; b < 8; ++b)
                vA[b] = *(const unsigned short*)(hseg + (size_t)sA[b] * 384);
            #pragma unroll
            for (int b = 0; b < 8; ++b) {
                int b0 = (int)(signed char)(vA[b] & 0xFF);
                int b1 = (int)(signed char)((vA[b] >> 8) & 0xFF);
                ax += wA[b] * (float)b0;
                ay += wA[b] * (float)b1;
            }
        }
    }

    float den = denl;
    #pragma unroll
    for (int msk = 1; msk < 64; msk <<= 1) den += __shfl_xor(den, msk);
    float r = 1.f / (den + 1e-9f);
    if (deg == 0) r = 0.f;

    if (active) {
        int fb = head * 128 + 2 * l;
        float2 bv = *(const float2*)(bias + fb);
        float vx = ax * r + bv.x; vx = (vx < 0.f) ? 0.01f * vx : vx;
        float vy = ay * r + bv.y; vy = (vy < 0.f) ? 0.01f * vy : vy;
        smS[nl][fb]     = vx;
        smS[nl][fb + 1] = vy;
    }
    __syncthreads();
    if (tid < 128) {
        int mn = tid >> 6;                 // node-local 0/1
        int n2 = blockIdx.x * 2 + mn;
        int f0i = (tid & 63) * 2, f1i = f0i + 1;
        float mx = 0.f, my = 0.f;
        if (n2 < N) {
            mx = (smS[mn][f0i] + smS[mn][128 + f0i] + smS[mn][256 + f0i]) * (1.0f / 3.0f);
            my = (smS[mn][f1i] + smS[mn][128 + f1i] + smS[mn][256 + f1i]) * (1.0f / 3.0f);
            short hx = f2bf(mx), hy = f2bf(my);
            unsigned ph = (unsigned)(unsigned short)hx | ((unsigned)(unsigned short)hy << 16);
            *(unsigned*)(outH + (size_t)n2 * 128 + f0i) = ph;
            if (outL) {
                short lx = f2bf(mx - bf2f(hx)), ly = f2bf(my - bf2f(hy));
                unsigned pl = (unsigned)(unsigned short)lx | ((unsigned)(unsigned short)ly << 16);
                *(unsigned*)(outL + (size_t)n2 * 128 + f0i) = pl;
            }
        }
        if (u2v) {
            // exact layer-2 logits from fp32 h2: el2/er2 = h2 · u2
            float a[6];
            #pragma unroll
            for (int v = 0; v < 6; ++v)
                a[v] = mx * u2v[v * 128 + f0i] + my * u2v[v * 128 + f1i];
            #pragma unroll
            for (int msk = 1; msk < 64; msk <<= 1)
                #pragma unroll
                for (int v = 0; v < 6; ++v)
                    a[v] += __shfl_xor(a[v], msk);
            if ((tid & 63) == 0 && n2 < N) {
                #pragma unroll
                for (int h = 0; h < 3; ++h) {
                    els2[(size_t)(n2 * 3 + h) * 2] = a[h * 2];
                    er2[n2 * 3 + h] = a[h * 2 + 1];
                }
            }
        }
    }
}

// ---------------------------------------------------------------------------
extern "C" void kernel_launch(void* const* d_in, const int* in_sizes, int n_in,
                              void* d_out, int out_size, void* d_ws, size_t ws_size,
                              hipStream_t stream)
{
    const float* in_feat = (const float*)d_in[0];
    const int*   src     = (const int*)d_in[1];
    const int*   dst     = (const int*)d_in[2];
    const float* W1  = (const float*)d_in[3];
    const float* al1 = (const float*)d_in[4];
    const float* ar1 = (const float*)d_in[5];
    const float* b1  = (const float*)d_in[6];
    const float* W2  = (const float*)d_in[7];
    const float* al2 = (const float*)d_in[8];
    const float* ar2 = (const float*)d_in[9];
    const float* b2  = (const float*)d_in[10];
    const float* lw1 = (const float*)d_in[11];
    const float* lb1 = (const float*)d_in[12];
    const float* lw2 = (const float*)d_in[13];
    const float* lb2 = (const float*)d_in[14];
    const float* lw3 = (const float*)d_in[15];
    const float* lb3 = (const float*)d_in[16];
    const float* lw4 = (const float*)d_in[17];
    const float* lb4 = (const float*)d_in[18];
    const float* lw5 = (const float*)d_in[19];
    const float* lb5 = (const float*)d_in[20];

    const int N = in_sizes[0] / 128;   // 50000
    const int E = in_sizes[1];         // 800000

    size_t o = 0;
    auto alloc = [&](size_t bytes) { size_t p = o; o = (o + bytes + 255) & ~(size_t)255; return p; };
    char* ws = (char*)d_ws;
    short* P1h = (short*)(ws + alloc((size_t)N * 128 * 2));
    short* P1l = (short*)(ws + alloc((size_t)N * 128 * 2));
    short* P2h = (short*)(ws + alloc((size_t)N * 128 * 2));
    unsigned char* Aq = (unsigned char*)(ws + alloc((size_t)N * 384));   // int8 gemm out
    float* els1 = (float*)(ws + alloc((size_t)N * 3 * 2 * 4));           // {el1, scale1}
    float* er1  = (float*)(ws + alloc((size_t)N * 3 * 4));
    float* els2 = (float*)(ws + alloc((size_t)N * 3 * 2 * 4));           // {el2, scale2}
    float* er2  = (float*)(ws + alloc((size_t)N * 3 * 4));
    float* u1   = (float*)(ws + alloc((size_t)6 * 128 * 4));
    float* u2   = (float*)(ws + alloc((size_t)6 * 128 * 4));
    int*   cnt  = (int*)(ws + alloc((size_t)N * 4));
    int*   off  = (int*)(ws + alloc((size_t)(N + 1) * 4));
    int*   bsum = (int*)(ws + alloc((size_t)4096));
    int*   csrc = (int*)(ws + alloc((size_t)E * 4));
    short* w1th = (short*)(ws + alloc((size_t)384 * 128 * 2));
    short* w2th = (short*)(ws + alloc((size_t)384 * 128 * 2));
    short* l1th = (short*)(ws + alloc((size_t)128 * 128 * 2));
    short* l1tl = (short*)(ws + alloc((size_t)128 * 128 * 2));
    short* l2th = (short*)(ws + alloc((size_t)128 * 128 * 2));
    short* l2tl = (short*)(ws + alloc((size_t)128 * 128 * 2));
    short* l3th = (short*)(ws + alloc((size_t)128 * 128 * 2));
    short* l3tl = (short*)(ws + alloc((size_t)128 * 128 * 2));
    short* l4th = (short*)(ws + alloc((size_t)128 * 128 * 2));
    short* l4tl = (short*)(ws + alloc((size_t)128 * 128 * 2));
    short* l5th = (short*)(ws + alloc((size_t)6 * 128 * 2));
    short* l5tl = (short*)(ws + alloc((size_t)6 * 128 * 2));
    (void)ws_size;

    float* out = (float*)d_out;

    // ---- fused prep: conv_split + weight transpose + u-vectors + hist
    hipMemsetAsync(cnt, 0, (size_t)N * 4, stream);
    int n4 = N * 128 / 4;
    int cb = (n4 + 255) / 256;
    int wb = (164608 + 255) / 256;
    int hb = (E + 255) / 256;
    prep_kernel<<<cb + wb + 1 + hb, 256, 0, stream>>>(
        in_feat, P1h, n4, cb, wb, dst, cnt, E,
        W1, W2, lw1, lw2, lw3, lw4, lw5,
        w1th, w2th, l1th, l1tl, l2th, l2tl,
        l3th, l3tl, l4th, l4tl, l5th, l5tl,
        al1, ar1, al2, ar2, u1, u2);

    // ---- CSR scan + scatter; exact layer-1 logits
    int nb = (N + 1023) / 1024;
    scan_block<<<nb, 1024, 0, stream>>>(cnt, off, bsum, N);
    scan_add2<<<(N + 255) / 256, 256, 0, stream>>>(off, bsum, N, nb);
    scatter_kernel<<<(E + 255) / 256, 256, 0, stream>>>(src, dst, off, cnt, csrc, E);
    node_el<<<(N + 3) / 4, 256, 0, stream>>>(in_feat, u1, els1, er1, N);

    int RB = (N + BM - 1) / BM;
    dim3 ggrid(3, RB);
    int AGB = (N + 1) / 2;

    // ---- GAT layer 1
    gemm_mfma<<<ggrid, 256, 0, stream>>>(P1h, w1th, Aq, els1, N, 384);
    agg_kernel<<<AGB, 384, 0, stream>>>(Aq, els1, er1, off, csrc, b1,
                                        P2h, nullptr, u2, els2, er2, N);

    // ---- GAT layer 2
    gemm_mfma<<<ggrid, 256, 0, stream>>>(P2h, w2th, Aq, els2, N, 384);
    agg_kernel<<<AGB, 384, 0, stream>>>(Aq, els2, er2, off, csrc, b2,
                                        P1h, P1l, nullptr, nullptr, nullptr, N);

    // ---- MLP head (fused lin1..lin5, 64-node blocks)
    int RBM = (N + MROWS - 1) / MROWS;
    mlp_fused<<<RBM, 256, 0, stream>>>(P1h, P1l,
                                       l1th, l1tl, l2th, l2tl, l3th, l3tl,
                                       l4th, l4tl, l5th, l5tl,
                                       lb1, lb2, lb3, lb4, lb5, out, N);
}

// Round 12
// 508.752 us; speedup vs baseline: 1.0044x; 1.0044x over previous
//
#include <hip/hip_runtime.h>
#include <hip/hip_bf16.h>

// ---------------------------------------------------------------------------
// GAT (2 GATConv + 5-layer MLP), MI355X.
// R16: gemm/mlp staging -> global_load_lds(16B) + both-sides XOR swizzle.
// R17-R21: elimination matrix -> agg latency-chain bound. R20 structure
//     (2 nodes/block, 384 thr, direct exp, 8-deep batch, barrier-free).
// R23 (WIN 495.7): int8 rowmax-scaled gather both layers, absmax 7.63e-6.
// R24 (NET-NEG): edge_w precompute. R25 (MIXED 511.0, absmax 5.72e-6):
//     single-term bf16 gemm + exact logits GOOD; agg1 u2v epilogue BAD
//     (+10 us: ~500cy serial tail on a short latency-bound block).
// R26: keep R25's gemm/logit decoupling; move layer-2 logits into a second
//     node_el pass over P2h (bf16, coalesced, throughput-bound, ~5 us).
//     agg reverted to the R23 loop exactly (outL nullable; agg1 writes
//     hi-plane only). Logits: u = W·a in fp32 -> layer-2 logit error only
//     from bf16 h2 (strictly better than R23). Predicted absmax ~6e-6.
// ---------------------------------------------------------------------------

typedef __attribute__((ext_vector_type(8))) short short8;   // 8 bf16 = 4 VGPR
typedef __attribute__((ext_vector_type(4))) float float4v;  // MFMA C/D

__device__ inline short f2bf(float x) {
    union { float f; unsigned u; } v; v.f = x;
    unsigned r = v.u + 0x7FFFu + ((v.u >> 16) & 1u);   // RNE
    return (short)(r >> 16);
}
__device__ inline float bf2f(short b) {
    union { float f; unsigned u; } v;
    v.u = ((unsigned)(unsigned short)b) << 16;
    return v.f;
}
__device__ inline short8 zero8() { short8 z = {0,0,0,0,0,0,0,0}; return z; }

// async global->LDS, 16 B per lane (dest = wave-uniform base + lane*16)
__device__ __forceinline__ void gl_lds16(const short* g, short* l) {
    __builtin_amdgcn_global_load_lds(
        (const __attribute__((address_space(1))) void*)g,
        (__attribute__((address_space(3))) void*)l,
        16, 0, 0);
}

// XOR swizzle for 16B slots within a 64B row (8-way -> 2-way, free per m136).
#define SW(r) ((((r) >> 2) ^ (r)) & 3)

#define BM 128
#define BN 128
#define BK 32
#define MSTR 136   // act row stride in shorts (272 B = 17x16B, breaks pow2)
#define MROWS 64   // mlp_fused rows per block

// ---------------------------------------------------------------------------
// Fused prep: [0,cb) conv (hi only) | [cb,cb+wb) weight transpose |
// [cb+wb] u-vectors (W·a per layer) | rest hist.
__global__ void prep_kernel(
    const float* __restrict__ in_feat, short* __restrict__ P1h,
    int n4, int cb, int wb,
    const int* __restrict__ dst, int* __restrict__ cnt, int E,
    const float* __restrict__ w1, const float* __restrict__ w2,
    const float* __restrict__ m1, const float* __restrict__ m2,
    const float* __restrict__ m3, const float* __restrict__ m4,
    const float* __restrict__ w5,
    short* __restrict__ w1h, short* __restrict__ w2h,
    short* __restrict__ m1h, short* __restrict__ m1l,
    short* __restrict__ m2h, short* __restrict__ m2l,
    short* __restrict__ m3h, short* __restrict__ m3l,
    short* __restrict__ m4h, short* __restrict__ m4l,
    short* __restrict__ w5h, short* __restrict__ w5l,
    const float* __restrict__ al1, const float* __restrict__ ar1,
    const float* __restrict__ al2, const float* __restrict__ ar2,
    float* __restrict__ u1, float* __restrict__ u2)
{
    int blk = blockIdx.x;
    if (blk < cb) {
        int i = blk * 256 + threadIdx.x;
        if (i >= n4) return;
        float4 v = *(const float4*)(in_feat + (size_t)i * 4);
        float xs[4] = {v.x, v.y, v.z, v.w};
        short hs[4];
        #pragma unroll
        for (int j = 0; j < 4; ++j) hs[j] = f2bf(xs[j]);
        *(uint2*)(P1h + (size_t)i * 4) = *(uint2*)hs;
    } else if (blk < cb + wb) {
        int j = (blk - cb) * 256 + threadIdx.x;
        const float* src; short* th; short* tl; int Nc, base;
        if      (j < 49152)  { src = w1; th = w1h; tl = nullptr; Nc = 384; base = 0; }
        else if (j < 98304)  { src = w2; th = w2h; tl = nullptr; Nc = 384; base = 49152; }
        else if (j < 114688) { src = m1; th = m1h; tl = m1l; Nc = 128; base = 98304; }
        else if (j < 131072) { src = m2; th = m2h; tl = m2l; Nc = 128; base = 114688; }
        else if (j < 147456) { src = m3; th = m3h; tl = m3l; Nc = 128; base = 131072; }
        else if (j < 163840) { src = m4; th = m4h; tl = m4l; Nc = 128; base = 147456; }
        else if (j < 164608) { src = w5; th = w5h; tl = w5l; Nc = 6;   base = 163840; }
        else return;
        int i = j - base;
        int k = i / Nc, c = i - k * Nc;
        float v = src[i];
        short h = f2bf(v);
        th[(size_t)c * 128 + k] = h;
        if (tl) tl[(size_t)c * 128 + k] = f2bf(v - bf2f(h));
    } else if (blk == cb + wb) {
        // u-vectors: u[(h*2+s)*128 + k] = sum_f W[k*384 + h*128 + f] * a[h*128+f]
        int t = threadIdx.x;
        const float* W  = (t < 128) ? w1 : w2;
        const float* av = (t < 128) ? al1 : al2;
        const float* rv = (t < 128) ? ar1 : ar2;
        float* u = (t < 128) ? u1 : u2;
        int k = t & 127;
        #pragma unroll
        for (int h = 0; h < 3; ++h) {
            float sl = 0.f, sr = 0.f;
            for (int f = 0; f < 128; ++f) {
                float wv = W[(size_t)k * 384 + h * 128 + f];
                sl += wv * av[h * 128 + f];
                sr += wv * rv[h * 128 + f];
            }
            u[(h * 2 + 0) * 128 + k] = sl;
            u[(h * 2 + 1) * 128 + k] = sr;
        }
    } else {
        int e = (blk - cb - wb - 1) * 256 + threadIdx.x;
        if (e < E) atomicAdd(&cnt[dst[e]], 1);
    }
}

// ---------------------------------------------------------------------------
// node_el: logits via associativity, el/er[n,h] = X[n,:]·u[h,side].
// BF16=false: fp32 X (layer 1, exact). BF16=true: bf16 X rows (layer 2).
// 4 nodes per 256-thr block (1 wave per node).
template <bool BF16>
__global__ __launch_bounds__(256) void node_el(
    const void* __restrict__ Xv, const float* __restrict__ u,
    float* __restrict__ els, float* __restrict__ er, int N)
{
    int n = blockIdx.x * 4 + (threadIdx.x >> 6);
    int l = threadIdx.x & 63;
    if (n >= N) return;
    float x0, x1;
    if (BF16) {
        unsigned v = *(const unsigned*)((const short*)Xv + (size_t)n * 128 + 2 * l);
        union { unsigned u; float f; } f0, f1;
        f0.u = v << 16; f1.u = v & 0xffff0000u;
        x0 = f0.f; x1 = f1.f;
    } else {
        float2 x = *(const float2*)((const float*)Xv + (size_t)n * 128 + 2 * l);
        x0 = x.x; x1 = x.y;
    }
    float a[6];
    #pragma unroll
    for (int v = 0; v < 6; ++v)
        a[v] = x0 * u[v * 128 + 2 * l] + x1 * u[v * 128 + 2 * l + 1];
    #pragma unroll
    for (int msk = 1; msk < 64; msk <<= 1)
        #pragma unroll
        for (int v = 0; v < 6; ++v)
            a[v] += __shfl_xor(a[v], msk);
    if (l == 0) {
        #pragma unroll
        for (int h = 0; h < 3; ++h) {
            els[(size_t)(n * 3 + h) * 2] = a[h * 2];
            er[n * 3 + h] = a[h * 2 + 1];
        }
    }
}

// ---------------------------------------------------------------------------
// GEMM (GAT layers): single-term bf16 (values only feed int8 quantizer;
// logits computed exactly elsewhere). One head per col-block (blockIdx.x).
// Outputs: int8 rowmax-quantized Cq + per-(row,head) scale -> els slot 1.
__global__ __launch_bounds__(256) void gemm_mfma(
    const short* __restrict__ Ahi, const short* __restrict__ Bth,
    unsigned char* __restrict__ Cq, float* __restrict__ els,
    int M, int Nc)
{
    __shared__ short Ah[BM * BK], Bh[BN * BK];

    int tid = threadIdx.x, lane = tid & 63, wave = tid >> 6;
    int l15 = lane & 15, q = lane >> 4;
    int rowBase = blockIdx.y * BM, colBase = blockIdx.x * BN;

    float4v acc[2][8];
    #pragma unroll
    for (int mt = 0; mt < 2; ++mt)
        #pragma unroll
        for (int nt = 0; nt < 8; ++nt)
            acc[mt][nt] = (float4v){0.f, 0.f, 0.f, 0.f};

    for (int k0 = 0; k0 < 128; k0 += BK) {
        #pragma unroll
        for (int i = 0; i < 2; ++i) {
            int cid = tid + i * 256;             // wave-uniform base + lane
            int r = cid >> 2, sub = cid & 3;
            int gs = (sub ^ SW(r)) * 8;
            gl_lds16(Ahi + (size_t)(rowBase + r) * 128 + k0 + gs, Ah + cid * 8);
            gl_lds16(Bth + (size_t)(colBase + r) * 128 + k0 + gs, Bh + cid * 8);
        }
        __syncthreads();

        short8 aH[2];
        #pragma unroll
        for (int mt = 0; mt < 2; ++mt) {
            int row = wave * 32 + mt * 16 + l15;
            int off = row * 32 + (q ^ SW(row)) * 8;
            aH[mt] = *(short8*)&Ah[off];
        }
        #pragma unroll
        for (int nt = 0; nt < 8; ++nt) {
            int row = nt * 16 + l15;
            int off = row * 32 + (q ^ SW(row)) * 8;
            short8 bH = *(short8*)&Bh[off];
            #pragma unroll
            for (int mt = 0; mt < 2; ++mt)
                acc[mt][nt] = __builtin_amdgcn_mfma_f32_16x16x32_bf16(aH[mt], bH, acc[mt][nt], 0, 0, 0);
        }
        __syncthreads();
    }

    // ---- int8 rowmax quantization: scale = rowmax/127 per (row, head)
    #pragma unroll
    for (int mt = 0; mt < 2; ++mt) {
        #pragma unroll
        for (int i = 0; i < 4; ++i) {
            float rm = 0.f;
            #pragma unroll
            for (int nt = 0; nt < 8; ++nt)
                rm = fmaxf(rm, fabsf(acc[mt][nt][i]));
            #pragma unroll
            for (int mask = 1; mask < 16; mask <<= 1)
                rm = fmaxf(rm, __shfl_xor(rm, mask));
            int r = rowBase + wave * 32 + mt * 16 + q * 4 + i;
            float inv = 127.f / fmaxf(rm, 1e-30f);
            if (l15 == 0 && r < M)
                els[(size_t)(r * 3 + blockIdx.x) * 2 + 1] = rm * (1.f / 127.f);
            #pragma unroll
            for (int nt = 0; nt < 8; ++nt) {
                int c = colBase + nt * 16 + l15;
                int qi = (int)rintf(acc[mt][nt][i] * inv);
                int qn = __shfl_xor(qi, 1);        // neighbor col c^1
                if (!(l15 & 1) && r < M && c < Nc) {
                    unsigned short pk = (unsigned short)((qi & 0xFF) | ((qn & 0xFF) << 8));
                    *(unsigned short*)(Cq + (size_t)r * Nc + c) = pk;
                }
            }
        }
    }
}

// ---------------------------------------------------------------------------
// Fused MLP head: 4x (128->128, bias, lrelu) + (128->6, bias) in one kernel.
__global__ __launch_bounds__(256) void mlp_fused(
    const short* __restrict__ Ph, const short* __restrict__ Pl,
    const short* __restrict__ w1h, const short* __restrict__ w1l,
    const short* __restrict__ w2h, const short* __restrict__ w2l,
    const short* __restrict__ w3h, const short* __restrict__ w3l,
    const short* __restrict__ w4h, const short* __restrict__ w4l,
    const short* __restrict__ w5h, const short* __restrict__ w5l,
    const float* __restrict__ b1, const float* __restrict__ b2,
    const float* __restrict__ b3, const float* __restrict__ b4,
    const float* __restrict__ b5,
    float* __restrict__ out, int M)
{
    __shared__ short AH[MROWS * MSTR], AL[MROWS * MSTR];
    __shared__ short WH[128 * BK], WL[128 * BK];

    int tid = threadIdx.x, lane = tid & 63, wave = tid >> 6;
    int l15 = lane & 15, q = lane >> 4;
    int rowBase = blockIdx.x * MROWS;

    #pragma unroll
    for (int s = 0; s < 4; ++s) {
        int idx = tid + s * 256;
        int r = idx >> 4, kq = (idx & 15) * 8;
        int gr = rowBase + r;
        short8 vh = zero8(), vl = zero8();
        if (gr < M) {
            vh = *(const short8*)(Ph + (size_t)gr * 128 + kq);
            vl = *(const short8*)(Pl + (size_t)gr * 128 + kq);
        }
        *(short8*)&AH[r * MSTR + kq] = vh;
        *(short8*)&AL[r * MSTR + kq] = vl;
    }

    const short* Whs[4] = {w1h, w2h, w3h, w4h};
    const short* Wls[4] = {w1l, w2l, w3l, w4l};
    const float* Bss[4] = {b1, b2, b3, b4};

    #pragma unroll
    for (int L = 0; L < 4; ++L) {
        float4v acc[8];
        #pragma unroll
        for (int nt = 0; nt < 8; ++nt)
            acc[nt] = (float4v){0.f, 0.f, 0.f, 0.f};

        for (int k0 = 0; k0 < 128; k0 += BK) {
            #pragma unroll
            for (int i = 0; i < 4; ++i) {          // i<2: hi plane, i>=2: lo
                int c2 = tid + (i & 1) * 256;       // 0..511
                int r = c2 >> 2, sub = c2 & 3;
                int gs = (sub ^ SW(r)) * 8;
                if (i < 2) gl_lds16(Whs[L] + (size_t)r * 128 + k0 + gs, WH + c2 * 8);
                else       gl_lds16(Wls[L] + (size_t)r * 128 + k0 + gs, WL + c2 * 8);
            }
            __syncthreads();
            int offa = (wave * 16 + l15) * MSTR + k0 + q * 8;
            short8 aH  = *(short8*)&AH[offa];
            short8 aL2 = *(short8*)&AL[offa];
            #pragma unroll
            for (int nt = 0; nt < 8; ++nt) {
                int row = nt * 16 + l15;
                int off = row * 32 + (q ^ SW(row)) * 8;
                short8 bH = *(short8*)&WH[off];
                short8 bL = *(short8*)&WL[off];
                acc[nt] = __builtin_amdgcn_mfma_f32_16x16x32_bf16(aH, bH, acc[nt], 0, 0, 0);
                acc[nt] = __builtin_amdgcn_mfma_f32_16x16x32_bf16(aH, bL, acc[nt], 0, 0, 0);
                acc[nt] = __builtin_amdgcn_mfma_f32_16x16x32_bf16(aL2, bH, acc[nt], 0, 0, 0);
            }
            __syncthreads();
        }
        #pragma unroll
        for (int nt = 0; nt < 8; ++nt) {
            int c = nt * 16 + l15;
            float bv = Bss[L][c];
            #pragma unroll
            for (int i = 0; i < 4; ++i) {
                int r = wave * 16 + q * 4 + i;
                float v = acc[nt][i] + bv;
                v = (v < 0.f) ? 0.01f * v : v;
                short hh = f2bf(v);
                AH[r * MSTR + c] = hh;
                AL[r * MSTR + c] = f2bf(v - bf2f(hh));
            }
        }
        __syncthreads();
    }

    float4v acc5 = (float4v){0.f, 0.f, 0.f, 0.f};
    for (int k0 = 0; k0 < 128; k0 += BK) {
        if (tid < 128) {
            int plane = tid >> 6, rem = tid & 63;
            int c = rem >> 2, sub = rem & 3;
            short8 v = zero8();
            if (c < 6)
                v = *(const short8*)((plane ? w5l : w5h) + (size_t)c * 128 + k0 + sub * 8);
            *(short8*)&((plane ? WL : WH)[c * 32 + (sub ^ SW(c)) * 8]) = v;
        }
        __syncthreads();
        int offa = (wave * 16 + l15) * MSTR + k0 + q * 8;
        short8 aH  = *(short8*)&AH[offa];
        short8 aL2 = *(short8*)&AL[offa];
        int offb = l15 * 32 + (q ^ SW(l15)) * 8;
        short8 bH = *(short8*)&WH[offb];
        short8 bL = *(short8*)&WL[offb];
        acc5 = __builtin_amdgcn_mfma_f32_16x16x32_bf16(aH, bH, acc5, 0, 0, 0);
        acc5 = __builtin_amdgcn_mfma_f32_16x16x32_bf16(aH, bL, acc5, 0, 0, 0);
        acc5 = __builtin_amdgcn_mfma_f32_16x16x32_bf16(aL2, bH, acc5, 0, 0, 0);
        __syncthreads();
    }
    if (l15 < 6) {
        float bv = b5[l15];
        #pragma unroll
        for (int i = 0; i < 4; ++i) {
            int r = rowBase + wave * 16 + q * 4 + i;
            if (r < M) out[(size_t)r * 6 + l15] = acc5[i] + bv;
        }
    }
}

// ---------------------------------------------------------------------------
// CSR build (hist lives in prep_kernel)
__global__ __launch_bounds__(1024) void scan_block(const int* __restrict__ cnt,
                                                   int* __restrict__ off,
                                                   int* __restrict__ bsum, int n)
{
    __shared__ int tmp[1024];
    int tid = threadIdx.x;
    int i = blockIdx.x * 1024 + tid;
    int v = (i < n) ? cnt[i] : 0;
    tmp[tid] = v;
    __syncthreads();
    for (int s = 1; s < 1024; s <<= 1) {
        int t = (tid >= s) ? tmp[tid - s] : 0;
        __syncthreads();
        tmp[tid] += t;
        __syncthreads();
    }
    if (i < n) off[i] = tmp[tid] - v;
    if (tid == 1023) bsum[blockIdx.x] = tmp[1023];
}

__global__ void scan_add2(int* __restrict__ off, const int* __restrict__ bsum,
                          int n, int nb)
{
    __shared__ int pre[64];
    int tid = threadIdx.x;
    if (tid < 64) {
        int v = (tid < nb) ? bsum[tid] : 0;
        #pragma unroll
        for (int s = 1; s < 64; s <<= 1) {
            int t = __shfl_up(v, s);
            if (tid >= s) v += t;
        }
        pre[tid] = v;
    }
    __syncthreads();
    int i = blockIdx.x * blockDim.x + tid;
    if (i < n) {
        int chunk = i >> 10;
        off[i] += chunk ? pre[chunk - 1] : 0;
    }
    if (i == 0) off[n] = pre[nb - 1];
}

__global__ void scatter_kernel(const int* __restrict__ src, const int* __restrict__ dst,
                               const int* __restrict__ off, int* __restrict__ cnt,
                               int* __restrict__ csrc, int E)
{
    int e = blockIdx.x * blockDim.x + threadIdx.x;
    if (e < E) {
        int d = dst[e];
        int p = atomicSub(&cnt[d], 1) - 1;
        csrc[off[d] + p] = src[e];
    }
}

// ---------------------------------------------------------------------------
// Fused edge-softmax + weighted gather + bias + lrelu + head-mean.
// R23 form exactly: in-loop {el,scale} float2 gather (L2-resident), int8
// values, direct exp, 8-deep batch, barrier-free chunk loop, 2 nodes/block.
// outL nullable (agg1 writes hi-plane only).
__global__ __launch_bounds__(384) void agg_kernel(
    const unsigned char* __restrict__ h8, const float* __restrict__ els,
    const float* __restrict__ er, const int* __restrict__ off,
    const int* __restrict__ csrc, const float* __restrict__ bias,
    short* __restrict__ outH, short* __restrict__ outL, int N)
{
    int tid = threadIdx.x;         // 0..383
    int u = tid >> 6;              // wave 0..5
    int nl = u / 3;                // node-local 0/1
    int head = u - nl * 3;         // 0..2
    int l = tid & 63;
    int n = blockIdx.x * 2 + nl;
    bool active = (n < N);

    __shared__ int   ssrcS[6][64];
    __shared__ float swS[6][64];
    __shared__ float smS[2][384];

    int beg = 0, deg = 0;
    float erv = 0.f;
    if (active) {
        beg = off[n];
        deg = off[n + 1] - beg;
        erv = er[n * 3 + head];
    }

    const unsigned char* hseg = h8 + head * 128 + l * 2;
    float ax = 0.f, ay = 0.f, denl = 0.f;

    for (int base = 0; base < deg; base += 64) {
        int cnt = min(64, deg - base);
        int s_l = 0; float w = 0.f, wS = 0.f;
        if (l < cnt) {
            s_l = csrc[beg + base + l];
            float2 e2 = *(const float2*)(els + (size_t)(s_l * 3 + head) * 2);
            float t = e2.x + erv;
            t = (t < 0.f) ? 0.2f * t : t;
            w = __expf(t);                 // direct exp: logits bounded
            wS = w * e2.y;                 // fold int8 scale into weight
        }
        denl += w;
        ssrcS[u][l] = s_l;                 // per-wave region: no barrier
        swS[u][l]   = wS;                  // (same-wave lgkmcnt ordering)
        for (int q0 = 0; q0 < cnt; q0 += 8) {
            int sA[8]; float wA[8]; unsigned vA[8];
            #pragma unroll
            for (int b = 0; b < 8; ++b) {
                int e = q0 + b;            // <= 63 always; pads have w=0,s=0
                sA[b] = ssrcS[u][e];
                wA[b] = swS[u][e];
            }
            #pragma unroll
            for (int b = 0; b < 8; ++b)
                vA[b] = *(const unsigned short*)(hseg + (size_t)sA[b] * 384);
            #pragma unroll
            for (int b = 0; b < 8; ++b) {
                int b0 = (int)(signed char)(vA[b] & 0xFF);
                int b1 = (int)(signed char)((vA[b] >> 8) & 0xFF);
                ax += wA[b] * (float)b0;
                ay += wA[b] * (float)b1;
            }
        }
    }

    float den = denl;
    #pragma unroll
    for (int msk = 1; msk < 64; msk <<= 1) den += __shfl_xor(den, msk);
    float r = 1.f / (den + 1e-9f);
    if (deg == 0) r = 0.f;

    if (active) {
        int fb = head * 128 + 2 * l;
        float2 bv = *(const float2*)(bias + fb);
        float vx = ax * r + bv.x; vx = (vx < 0.f) ? 0.01f * vx : vx;
        float vy = ay * r + bv.y; vy = (vy < 0.f) ? 0.01f * vy : vy;
        smS[nl][fb]     = vx;
        smS[nl][fb + 1] = vy;
    }
    __syncthreads();
    if (tid < 128) {
        int mn = tid >> 6;                 // node-local 0/1
        int n2 = blockIdx.x * 2 + mn;
        if (n2 < N) {
            int f0i = (tid & 63) * 2, f1i = f0i + 1;
            float mx = (smS[mn][f0i] + smS[mn][128 + f0i] + smS[mn][256 + f0i]) * (1.0f / 3.0f);
            float my = (smS[mn][f1i] + smS[mn][128 + f1i] + smS[mn][256 + f1i]) * (1.0f / 3.0f);
            short hx = f2bf(mx), hy = f2bf(my);
            unsigned ph = (unsigned)(unsigned short)hx | ((unsigned)(unsigned short)hy << 16);
            *(unsigned*)(outH + (size_t)n2 * 128 + f0i) = ph;
            if (outL) {
                short lx = f2bf(mx - bf2f(hx)), ly = f2bf(my - bf2f(hy));
                unsigned pl = (unsigned)(unsigned short)lx | ((unsigned)(unsigned short)ly << 16);
                *(unsigned*)(outL + (size_t)n2 * 128 + f0i) = pl;
            }
        }
    }
}

// ---------------------------------------------------------------------------
extern "C" void kernel_launch(void* const* d_in, const int* in_sizes, int n_in,
                              void* d_out, int out_size, void* d_ws, size_t ws_size,
                              hipStream_t stream)
{
    const float* in_feat = (const float*)d_in[0];
    const int*   src     = (const int*)d_in[1];
    const int*   dst     = (const int*)d_in[2];
    const float* W1  = (const float*)d_in[3];
    const float* al1 = (const float*)d_in[4];
    const float* ar1 = (const float*)d_in[5];
    const float* b1  = (const float*)d_in[6];
    const float* W2  = (const float*)d_in[7];
    const float* al2 = (const float*)d_in[8];
    const float* ar2 = (const float*)d_in[9];
    const float* b2  = (const float*)d_in[10];
    const float* lw1 = (const float*)d_in[11];
    const float* lb1 = (const float*)d_in[12];
    const float* lw2 = (const float*)d_in[13];
    const float* lb2 = (const float*)d_in[14];
    const float* lw3 = (const float*)d_in[15];
    const float* lb3 = (const float*)d_in[16];
    const float* lw4 = (const float*)d_in[17];
    const float* lb4 = (const float*)d_in[18];
    const float* lw5 = (const float*)d_in[19];
    const float* lb5 = (const float*)d_in[20];

    const int N = in_sizes[0] / 128;   // 50000
    const int E = in_sizes[1];         // 800000

    size_t o = 0;
    auto alloc = [&](size_t bytes) { size_t p = o; o = (o + bytes + 255) & ~(size_t)255; return p; };
    char* ws = (char*)d_ws;
    short* P1h = (short*)(ws + alloc((size_t)N * 128 * 2));
    short* P1l = (short*)(ws + alloc((size_t)N * 128 * 2));
    short* P2h = (short*)(ws + alloc((size_t)N * 128 * 2));
    unsigned char* Aq = (unsigned char*)(ws + alloc((size_t)N * 384));   // int8 gemm out
    float* els1 = (float*)(ws + alloc((size_t)N * 3 * 2 * 4));           // {el1, scale1}
    float* er1  = (float*)(ws + alloc((size_t)N * 3 * 4));
    float* els2 = (float*)(ws + alloc((size_t)N * 3 * 2 * 4));           // {el2, scale2}
    float* er2  = (float*)(ws + alloc((size_t)N * 3 * 4));
    float* u1   = (float*)(ws + alloc((size_t)6 * 128 * 4));
    float* u2   = (float*)(ws + alloc((size_t)6 * 128 * 4));
    int*   cnt  = (int*)(ws + alloc((size_t)N * 4));
    int*   off  = (int*)(ws + alloc((size_t)(N + 1) * 4));
    int*   bsum = (int*)(ws + alloc((size_t)4096));
    int*   csrc = (int*)(ws + alloc((size_t)E * 4));
    short* w1th = (short*)(ws + alloc((size_t)384 * 128 * 2));
    short* w2th = (short*)(ws + alloc((size_t)384 * 128 * 2));
    short* l1th = (short*)(ws + alloc((size_t)128 * 128 * 2));
    short* l1tl = (short*)(ws + alloc((size_t)128 * 128 * 2));
    short* l2th = (short*)(ws + alloc((size_t)128 * 128 * 2));
    short* l2tl = (short*)(ws + alloc((size_t)128 * 128 * 2));
    short* l3th = (short*)(ws + alloc((size_t)128 * 128 * 2));
    short* l3tl = (short*)(ws + alloc((size_t)128 * 128 * 2));
    short* l4th = (short*)(ws + alloc((size_t)128 * 128 * 2));
    short* l4tl = (short*)(ws + alloc((size_t)128 * 128 * 2));
    short* l5th = (short*)(ws + alloc((size_t)6 * 128 * 2));
    short* l5tl = (short*)(ws + alloc((size_t)6 * 128 * 2));
    (void)ws_size;

    float* out = (float*)d_out;

    // ---- fused prep: conv_split + weight transpose + u-vectors + hist
    hipMemsetAsync(cnt, 0, (size_t)N * 4, stream);
    int n4 = N * 128 / 4;
    int cb = (n4 + 255) / 256;
    int wb = (164608 + 255) / 256;
    int hb = (E + 255) / 256;
    prep_kernel<<<cb + wb + 1 + hb, 256, 0, stream>>>(
        in_feat, P1h, n4, cb, wb, dst, cnt, E,
        W1, W2, lw1, lw2, lw3, lw4, lw5,
        w1th, w2th, l1th, l1tl, l2th, l2tl,
        l3th, l3tl, l4th, l4tl, l5th, l5tl,
        al1, ar1, al2, ar2, u1, u2);

    // ---- CSR scan + scatter; exact layer-1 logits
    int nb = (N + 1023) / 1024;
    scan_block<<<nb, 1024, 0, stream>>>(cnt, off, bsum, N);
    scan_add2<<<(N + 255) / 256, 256, 0, stream>>>(off, bsum, N, nb);
    scatter_kernel<<<(E + 255) / 256, 256, 0, stream>>>(src, dst, off, cnt, csrc, E);
    node_el<false><<<(N + 3) / 4, 256, 0, stream>>>(in_feat, u1, els1, er1, N);

    int RB = (N + BM - 1) / BM;
    dim3 ggrid(3, RB);
    int AGB = (N + 1) / 2;

    // ---- GAT layer 1
    gemm_mfma<<<ggrid, 256, 0, stream>>>(P1h, w1th, Aq, els1, N, 384);
    agg_kernel<<<AGB, 384, 0, stream>>>(Aq, els1, er1, off, csrc, b1,
                                        P2h, nullptr, N);

    // ---- layer-2 logits from bf16 h2 (throughput-bound, out of agg)
    node_el<true><<<(N + 3) / 4, 256, 0, stream>>>(P2h, u2, els2, er2, N);

    // ---- GAT layer 2
    gemm_mfma<<<ggrid, 256, 0, stream>>>(P2h, w2th, Aq, els2, N, 384);
    agg_kernel<<<AGB, 384, 0, stream>>>(Aq, els2, er2, off, csrc, b2,
                                        P1h, P1l, N);

    // ---- MLP head (fused lin1..lin5, 64-node blocks)
    int RBM = (N + MROWS - 1) / MROWS;
    mlp_fused<<<RBM, 256, 0, stream>>>(P1h, P1l,
                                       l1th, l1tl, l2th, l2tl, l3th, l3tl,
                                       l4th, l4tl, l5th, l5tl,
                                       lb1, lb2, lb3, lb4, lb5, out, N);
}

// Round 13
// 500.057 us; speedup vs baseline: 1.0218x; 1.0174x over previous
//
#include <hip/hip_runtime.h>
#include <hip/hip_bf16.h>

// ---------------------------------------------------------------------------
// GAT (2 GATConv + 5-layer MLP), MI355X.
// R16: gemm/mlp staging -> global_load_lds(16B) + both-sides XOR swizzle.
// R17-R21: elimination matrix -> agg latency-chain bound. R20 structure
//     (2 nodes/block, 384 thr, direct exp, 8-deep batch, barrier-free).
// R23 (495.7): int8 rowmax-scaled gather both layers, absmax 7.63e-6.
// R25/R26: single-term bf16 gemm + exact logit decoupling (absmax 5.72e-6)
//     but +2 launches ate the gains (508.8). Cross-round fit: each small
//     launch costs ~6-8 us end-to-end; gemms are drain-bound (R22) so
//     lighter gemms saved ~0. The ~320us non-agg bucket is launch-bound.
// R27: dispatch count 13 -> 10.
//     (1) l1_mega: gemm1 || scatter || node_el1 in ONE launch (block-range
//         split; all depend only on {prep, scan_add2}; overlap on idle CUs).
//     (2) layer-2 logits fused into gemm2's K-loop from A fragments
//         (u2 slice in LDS, 32 FMA/K-step under the drain; q-reduce in
//         epilogue). No serial tail on a latency-bound kernel (R25 lesson).
//     agg/mlp/prep/scans untouched. Predicted absmax ~5.7e-6.
// ---------------------------------------------------------------------------

typedef __attribute__((ext_vector_type(8))) short short8;   // 8 bf16 = 4 VGPR
typedef __attribute__((ext_vector_type(4))) float float4v;  // MFMA C/D

__device__ inline short f2bf(float x) {
    union { float f; unsigned u; } v; v.f = x;
    unsigned r = v.u + 0x7FFFu + ((v.u >> 16) & 1u);   // RNE
    return (short)(r >> 16);
}
__device__ inline float bf2f(short b) {
    union { float f; unsigned u; } v;
    v.u = ((unsigned)(unsigned short)b) << 16;
    return v.f;
}
__device__ inline short8 zero8() { short8 z = {0,0,0,0,0,0,0,0}; return z; }

// async global->LDS, 16 B per lane (dest = wave-uniform base + lane*16)
__device__ __forceinline__ void gl_lds16(const short* g, short* l) {
    __builtin_amdgcn_global_load_lds(
        (const __attribute__((address_space(1))) void*)g,
        (__attribute__((address_space(3))) void*)l,
        16, 0, 0);
}

// XOR swizzle for 16B slots within a 64B row (8-way -> 2-way, free per m136).
#define SW(r) ((((r) >> 2) ^ (r)) & 3)

#define BM 128
#define BN 128
#define BK 32
#define MSTR 136   // act row stride in shorts (272 B = 17x16B, breaks pow2)
#define MROWS 64   // mlp_fused rows per block

// ---------------------------------------------------------------------------
// Fused prep: [0,cb) conv (hi only) | [cb,cb+wb) weight transpose |
// [cb+wb] u-vectors (W·a per layer) | rest hist.
__global__ void prep_kernel(
    const float* __restrict__ in_feat, short* __restrict__ P1h,
    int n4, int cb, int wb,
    const int* __restrict__ dst, int* __restrict__ cnt, int E,
    const float* __restrict__ w1, const float* __restrict__ w2,
    const float* __restrict__ m1, const float* __restrict__ m2,
    const float* __restrict__ m3, const float* __restrict__ m4,
    const float* __restrict__ w5,
    short* __restrict__ w1h, short* __restrict__ w2h,
    short* __restrict__ m1h, short* __restrict__ m1l,
    short* __restrict__ m2h, short* __restrict__ m2l,
    short* __restrict__ m3h, short* __restrict__ m3l,
    short* __restrict__ m4h, short* __restrict__ m4l,
    short* __restrict__ w5h, short* __restrict__ w5l,
    const float* __restrict__ al1, const float* __restrict__ ar1,
    const float* __restrict__ al2, const float* __restrict__ ar2,
    float* __restrict__ u1, float* __restrict__ u2)
{
    int blk = blockIdx.x;
    if (blk < cb) {
        int i = blk * 256 + threadIdx.x;
        if (i >= n4) return;
        float4 v = *(const float4*)(in_feat + (size_t)i * 4);
        float xs[4] = {v.x, v.y, v.z, v.w};
        short hs[4];
        #pragma unroll
        for (int j = 0; j < 4; ++j) hs[j] = f2bf(xs[j]);
        *(uint2*)(P1h + (size_t)i * 4) = *(uint2*)hs;
    } else if (blk < cb + wb) {
        int j = (blk - cb) * 256 + threadIdx.x;
        const float* src; short* th; short* tl; int Nc, base;
        if      (j < 49152)  { src = w1; th = w1h; tl = nullptr; Nc = 384; base = 0; }
        else if (j < 98304)  { src = w2; th = w2h; tl = nullptr; Nc = 384; base = 49152; }
        else if (j < 114688) { src = m1; th = m1h; tl = m1l; Nc = 128; base = 98304; }
        else if (j < 131072) { src = m2; th = m2h; tl = m2l; Nc = 128; base = 114688; }
        else if (j < 147456) { src = m3; th = m3h; tl = m3l; Nc = 128; base = 131072; }
        else if (j < 163840) { src = m4; th = m4h; tl = m4l; Nc = 128; base = 147456; }
        else if (j < 164608) { src = w5; th = w5h; tl = w5l; Nc = 6;   base = 163840; }
        else return;
        int i = j - base;
        int k = i / Nc, c = i - k * Nc;
        float v = src[i];
        short h = f2bf(v);
        th[(size_t)c * 128 + k] = h;
        if (tl) tl[(size_t)c * 128 + k] = f2bf(v - bf2f(h));
    } else if (blk == cb + wb) {
        // u-vectors: u[(h*2+s)*128 + k] = sum_f W[k*384 + h*128 + f] * a[h*128+f]
        int t = threadIdx.x;
        const float* W  = (t < 128) ? w1 : w2;
        const float* av = (t < 128) ? al1 : al2;
        const float* rv = (t < 128) ? ar1 : ar2;
        float* u = (t < 128) ? u1 : u2;
        int k = t & 127;
        #pragma unroll
        for (int h = 0; h < 3; ++h) {
            float sl = 0.f, sr = 0.f;
            for (int f = 0; f < 128; ++f) {
                float wv = W[(size_t)k * 384 + h * 128 + f];
                sl += wv * av[h * 128 + f];
                sr += wv * rv[h * 128 + f];
            }
            u[(h * 2 + 0) * 128 + k] = sl;
            u[(h * 2 + 1) * 128 + k] = sr;
        }
    } else {
        int e = (blk - cb - wb - 1) * 256 + threadIdx.x;
        if (e < E) atomicAdd(&cnt[dst[e]], 1);
    }
}

// ---------------------------------------------------------------------------
// GEMM body (device fn): single-term bf16, int8 rowmax quantize.
// LOG=true additionally computes this head's logits el/er = A-row · u
// from the in-register A fragments (u slice preloaded to LDS).
template <bool LOG>
__device__ __forceinline__ void gemm_body(
    const short* __restrict__ Ahi, const short* __restrict__ Bth,
    unsigned char* __restrict__ Cq, float* __restrict__ els,
    float* __restrict__ erv, const float* __restrict__ uvec,
    int M, int Nc, int head, int rby)
{
    __shared__ short Ah[BM * BK], Bh[BN * BK];
    __shared__ float uL[2][128];

    int tid = threadIdx.x, lane = tid & 63, wave = tid >> 6;
    int l15 = lane & 15, q = lane >> 4;
    int rowBase = rby * BM, colBase = head * BN;

    if (LOG) {
        int s = tid >> 7, k = tid & 127;       // 256 threads cover [2][128]
        uL[s][k] = uvec[(head * 2 + s) * 128 + k];
    }

    float4v acc[2][8];
    #pragma unroll
    for (int mt = 0; mt < 2; ++mt)
        #pragma unroll
        for (int nt = 0; nt < 8; ++nt)
            acc[mt][nt] = (float4v){0.f, 0.f, 0.f, 0.f};
    float pl[2] = {0.f, 0.f}, pr[2] = {0.f, 0.f};

    for (int k0 = 0; k0 < 128; k0 += BK) {
        #pragma unroll
        for (int i = 0; i < 2; ++i) {
            int cid = tid + i * 256;             // wave-uniform base + lane
            int r = cid >> 2, sub = cid & 3;
            int gs = (sub ^ SW(r)) * 8;
            gl_lds16(Ahi + (size_t)(rowBase + r) * 128 + k0 + gs, Ah + cid * 8);
            gl_lds16(Bth + (size_t)(colBase + r) * 128 + k0 + gs, Bh + cid * 8);
        }
        __syncthreads();

        short8 aH[2];
        #pragma unroll
        for (int mt = 0; mt < 2; ++mt) {
            int row = wave * 32 + mt * 16 + l15;
            int off = row * 32 + (q ^ SW(row)) * 8;
            aH[mt] = *(short8*)&Ah[off];
        }
        if (LOG) {
            #pragma unroll
            for (int mt = 0; mt < 2; ++mt)
                #pragma unroll
                for (int j = 0; j < 8; ++j) {
                    float av = bf2f(aH[mt][j]);
                    int k = k0 + q * 8 + j;      // lane's global k-slice is q
                    pl[mt] += av * uL[0][k];
                    pr[mt] += av * uL[1][k];
                }
        }
        #pragma unroll
        for (int nt = 0; nt < 8; ++nt) {
            int row = nt * 16 + l15;
            int off = row * 32 + (q ^ SW(row)) * 8;
            short8 bH = *(short8*)&Bh[off];
            #pragma unroll
            for (int mt = 0; mt < 2; ++mt)
                acc[mt][nt] = __builtin_amdgcn_mfma_f32_16x16x32_bf16(aH[mt], bH, acc[mt][nt], 0, 0, 0);
        }
        __syncthreads();
    }

    if (LOG) {
        #pragma unroll
        for (int mt = 0; mt < 2; ++mt) {
            pl[mt] += __shfl_xor(pl[mt], 16);
            pl[mt] += __shfl_xor(pl[mt], 32);
            pr[mt] += __shfl_xor(pr[mt], 16);
            pr[mt] += __shfl_xor(pr[mt], 32);
            int r = rowBase + wave * 32 + mt * 16 + l15;
            if (q == 0 && r < M) {
                els[(size_t)(r * 3 + head) * 2] = pl[mt];
                erv[r * 3 + head] = pr[mt];
            }
        }
    }

    // ---- int8 rowmax quantization: scale = rowmax/127 per (row, head)
    #pragma unroll
    for (int mt = 0; mt < 2; ++mt) {
        #pragma unroll
        for (int i = 0; i < 4; ++i) {
            float rm = 0.f;
            #pragma unroll
            for (int nt = 0; nt < 8; ++nt)
                rm = fmaxf(rm, fabsf(acc[mt][nt][i]));
            #pragma unroll
            for (int mask = 1; mask < 16; mask <<= 1)
                rm = fmaxf(rm, __shfl_xor(rm, mask));
            int r = rowBase + wave * 32 + mt * 16 + q * 4 + i;
            float inv = 127.f / fmaxf(rm, 1e-30f);
            if (l15 == 0 && r < M)
                els[(size_t)(r * 3 + head) * 2 + 1] = rm * (1.f / 127.f);
            #pragma unroll
            for (int nt = 0; nt < 8; ++nt) {
                int c = head * BN + nt * 16 + l15;
                int qi = (int)rintf(acc[mt][nt][i] * inv);
                int qn = __shfl_xor(qi, 1);        // neighbor col c^1
                if (!(l15 & 1) && r < M && c < Nc) {
                    unsigned short pk = (unsigned short)((qi & 0xFF) | ((qn & 0xFF) << 8));
                    *(unsigned short*)(Cq + (size_t)r * Nc + c) = pk;
                }
            }
        }
    }
}

// ---------------------------------------------------------------------------
// L1 mega-launch: [0,NG) gemm1 blocks | [NG,NG+NS) scatter (grid-stride) |
// rest node_el1 (exact fp32 layer-1 logits, grid-stride). All three depend
// only on {prep, scan_add2}; co-resident overlap replaces 3 serialized
// launches.
__global__ __launch_bounds__(256) void l1_mega(
    const short* __restrict__ P1h, const short* __restrict__ w1th,
    unsigned char* __restrict__ Cq, float* __restrict__ els1, int M, int Nc,
    int NG,
    const int* __restrict__ src, const int* __restrict__ dst,
    const int* __restrict__ off, int* __restrict__ cnt,
    int* __restrict__ csrc, int E, int NS,
    const float* __restrict__ X, const float* __restrict__ u1,
    float* __restrict__ er1, int N, int NE)
{
    int b = blockIdx.x;
    if (b < NG) {
        gemm_body<false>(P1h, w1th, Cq, els1, nullptr, nullptr,
                         M, Nc, b % 3, b / 3);
        return;
    }
    b -= NG;
    if (b < NS) {
        for (int e = b * 256 + threadIdx.x; e < E; e += NS * 256) {
            int d = dst[e];
            int p = atomicSub(&cnt[d], 1) - 1;
            csrc[off[d] + p] = src[e];
        }
        return;
    }
    b -= NS;
    int wv = threadIdx.x >> 6, l = threadIdx.x & 63;
    for (int n = b * 4 + wv; n < N; n += NE * 4) {
        float2 x = *(const float2*)(X + (size_t)n * 128 + 2 * l);
        float a[6];
        #pragma unroll
        for (int v = 0; v < 6; ++v)
            a[v] = x.x * u1[v * 128 + 2 * l] + x.y * u1[v * 128 + 2 * l + 1];
        #pragma unroll
        for (int msk = 1; msk < 64; msk <<= 1)
            #pragma unroll
            for (int v = 0; v < 6; ++v)
                a[v] += __shfl_xor(a[v], msk);
        if (l == 0) {
            #pragma unroll
            for (int h = 0; h < 3; ++h) {
                els1[(size_t)(n * 3 + h) * 2] = a[h * 2];
                er1[n * 3 + h] = a[h * 2 + 1];
            }
        }
    }
}

// gemm for layer 2: + fused exact-u2 logits from A fragments.
__global__ __launch_bounds__(256) void gemm_l2(
    const short* __restrict__ P2h, const short* __restrict__ w2th,
    unsigned char* __restrict__ Cq, float* __restrict__ els2,
    float* __restrict__ er2, const float* __restrict__ u2, int M, int Nc)
{
    gemm_body<true>(P2h, w2th, Cq, els2, er2, u2, M, Nc,
                    blockIdx.x, blockIdx.y);
}

// ---------------------------------------------------------------------------
// Fused MLP head: 4x (128->128, bias, lrelu) + (128->6, bias) in one kernel.
__global__ __launch_bounds__(256) void mlp_fused(
    const short* __restrict__ Ph, const short* __restrict__ Pl,
    const short* __restrict__ w1h, const short* __restrict__ w1l,
    const short* __restrict__ w2h, const short* __restrict__ w2l,
    const short* __restrict__ w3h, const short* __restrict__ w3l,
    const short* __restrict__ w4h, const short* __restrict__ w4l,
    const short* __restrict__ w5h, const short* __restrict__ w5l,
    const float* __restrict__ b1, const float* __restrict__ b2,
    const float* __restrict__ b3, const float* __restrict__ b4,
    const float* __restrict__ b5,
    float* __restrict__ out, int M)
{
    __shared__ short AH[MROWS * MSTR], AL[MROWS * MSTR];
    __shared__ short WH[128 * BK], WL[128 * BK];

    int tid = threadIdx.x, lane = tid & 63, wave = tid >> 6;
    int l15 = lane & 15, q = lane >> 4;
    int rowBase = blockIdx.x * MROWS;

    #pragma unroll
    for (int s = 0; s < 4; ++s) {
        int idx = tid + s * 256;
        int r = idx >> 4, kq = (idx & 15) * 8;
        int gr = rowBase + r;
        short8 vh = zero8(), vl = zero8();
        if (gr < M) {
            vh = *(const short8*)(Ph + (size_t)gr * 128 + kq);
            vl = *(const short8*)(Pl + (size_t)gr * 128 + kq);
        }
        *(short8*)&AH[r * MSTR + kq] = vh;
        *(short8*)&AL[r * MSTR + kq] = vl;
    }

    const short* Whs[4] = {w1h, w2h, w3h, w4h};
    const short* Wls[4] = {w1l, w2l, w3l, w4l};
    const float* Bss[4] = {b1, b2, b3, b4};

    #pragma unroll
    for (int L = 0; L < 4; ++L) {
        float4v acc[8];
        #pragma unroll
        for (int nt = 0; nt < 8; ++nt)
            acc[nt] = (float4v){0.f, 0.f, 0.f, 0.f};

        for (int k0 = 0; k0 < 128; k0 += BK) {
            #pragma unroll
            for (int i = 0; i < 4; ++i) {          // i<2: hi plane, i>=2: lo
                int c2 = tid + (i & 1) * 256;       // 0..511
                int r = c2 >> 2, sub = c2 & 3;
                int gs = (sub ^ SW(r)) * 8;
                if (i < 2) gl_lds16(Whs[L] + (size_t)r * 128 + k0 + gs, WH + c2 * 8);
                else       gl_lds16(Wls[L] + (size_t)r * 128 + k0 + gs, WL + c2 * 8);
            }
            __syncthreads();
            int offa = (wave * 16 + l15) * MSTR + k0 + q * 8;
            short8 aH  = *(short8*)&AH[offa];
            short8 aL2 = *(short8*)&AL[offa];
            #pragma unroll
            for (int nt = 0; nt < 8; ++nt) {
                int row = nt * 16 + l15;
                int off = row * 32 + (q ^ SW(row)) * 8;
                short8 bH = *(short8*)&WH[off];
                short8 bL = *(short8*)&WL[off];
                acc[nt] = __builtin_amdgcn_mfma_f32_16x16x32_bf16(aH, bH, acc[nt], 0, 0, 0);
                acc[nt] = __builtin_amdgcn_mfma_f32_16x16x32_bf16(aH, bL, acc[nt], 0, 0, 0);
                acc[nt] = __builtin_amdgcn_mfma_f32_16x16x32_bf16(aL2, bH, acc[nt], 0, 0, 0);
            }
            __syncthreads();
        }
        #pragma unroll
        for (int nt = 0; nt < 8; ++nt) {
            int c = nt * 16 + l15;
            float bv = Bss[L][c];
            #pragma unroll
            for (int i = 0; i < 4; ++i) {
                int r = wave * 16 + q * 4 + i;
                float v = acc[nt][i] + bv;
                v = (v < 0.f) ? 0.01f * v : v;
                short hh = f2bf(v);
                AH[r * MSTR + c] = hh;
                AL[r * MSTR + c] = f2bf(v - bf2f(hh));
            }
        }
        __syncthreads();
    }

    float4v acc5 = (float4v){0.f, 0.f, 0.f, 0.f};
    for (int k0 = 0; k0 < 128; k0 += BK) {
        if (tid < 128) {
            int plane = tid >> 6, rem = tid & 63;
            int c = rem >> 2, sub = rem & 3;
            short8 v = zero8();
            if (c < 6)
                v = *(const short8*)((plane ? w5l : w5h) + (size_t)c * 128 + k0 + sub * 8);
            *(short8*)&((plane ? WL : WH)[c * 32 + (sub ^ SW(c)) * 8]) = v;
        }
        __syncthreads();
        int offa = (wave * 16 + l15) * MSTR + k0 + q * 8;
        short8 aH  = *(short8*)&AH[offa];
        short8 aL2 = *(short8*)&AL[offa];
        int offb = l15 * 32 + (q ^ SW(l15)) * 8;
        short8 bH = *(short8*)&WH[offb];
        short8 bL = *(short8*)&WL[offb];
        acc5 = __builtin_amdgcn_mfma_f32_16x16x32_bf16(aH, bH, acc5, 0, 0, 0);
        acc5 = __builtin_amdgcn_mfma_f32_16x16x32_bf16(aH, bL, acc5, 0, 0, 0);
        acc5 = __builtin_amdgcn_mfma_f32_16x16x32_bf16(aL2, bH, acc5, 0, 0, 0);
        __syncthreads();
    }
    if (l15 < 6) {
        float bv = b5[l15];
        #pragma unroll
        for (int i = 0; i < 4; ++i) {
            int r = rowBase + wave * 16 + q * 4 + i;
            if (r < M) out[(size_t)r * 6 + l15] = acc5[i] + bv;
        }
    }
}

// ---------------------------------------------------------------------------
// CSR build (hist lives in prep_kernel)
__global__ __launch_bounds__(1024) void scan_block(const int* __restrict__ cnt,
                                                   int* __restrict__ off,
                                                   int* __restrict__ bsum, int n)
{
    __shared__ int tmp[1024];
    int tid = threadIdx.x;
    int i = blockIdx.x * 1024 + tid;
    int v = (i < n) ? cnt[i] : 0;
    tmp[tid] = v;
    __syncthreads();
    for (int s = 1; s < 1024; s <<= 1) {
        int t = (tid >= s) ? tmp[tid - s] : 0;
        __syncthreads();
        tmp[tid] += t;
        __syncthreads();
    }
    if (i < n) off[i] = tmp[tid] - v;
    if (tid == 1023) bsum[blockIdx.x] = tmp[1023];
}

__global__ void scan_add2(int* __restrict__ off, const int* __restrict__ bsum,
                          int n, int nb)
{
    __shared__ int pre[64];
    int tid = threadIdx.x;
    if (tid < 64) {
        int v = (tid < nb) ? bsum[tid] : 0;
        #pragma unroll
        for (int s = 1; s < 64; s <<= 1) {
            int t = __shfl_up(v, s);
            if (tid >= s) v += t;
        }
        pre[tid] = v;
    }
    __syncthreads();
    int i = blockIdx.x * blockDim.x + tid;
    if (i < n) {
        int chunk = i >> 10;
        off[i] += chunk ? pre[chunk - 1] : 0;
    }
    if (i == 0) off[n] = pre[nb - 1];
}

// ---------------------------------------------------------------------------
// Fused edge-softmax + weighted gather + bias + lrelu + head-mean.
// R23 form exactly: in-loop {el,scale} float2 gather (L2-resident), int8
// values, direct exp, 8-deep batch, barrier-free chunk loop, 2 nodes/block.
// outL nullable (agg1 writes hi-plane only).
__global__ __launch_bounds__(384) void agg_kernel(
    const unsigned char* __restrict__ h8, const float* __restrict__ els,
    const float* __restrict__ er, const int* __restrict__ off,
    const int* __restrict__ csrc, const float* __restrict__ bias,
    short* __restrict__ outH, short* __restrict__ outL, int N)
{
    int tid = threadIdx.x;         // 0..383
    int u = tid >> 6;              // wave 0..5
    int nl = u / 3;                // node-local 0/1
    int head = u - nl * 3;         // 0..2
    int l = tid & 63;
    int n = blockIdx.x * 2 + nl;
    bool active = (n < N);

    __shared__ int   ssrcS[6][64];
    __shared__ float swS[6][64];
    __shared__ float smS[2][384];

    int beg = 0, deg = 0;
    float erv = 0.f;
    if (active) {
        beg = off[n];
        deg = off[n + 1] - beg;
        erv = er[n * 3 + head];
    }

    const unsigned char* hseg = h8 + head * 128 + l * 2;
    float ax = 0.f, ay = 0.f, denl = 0.f;

    for (int base = 0; base < deg; base += 64) {
        int cnt = min(64, deg - base);
        int s_l = 0; float w = 0.f, wS = 0.f;
        if (l < cnt) {
            s_l = csrc[beg + base + l];
            float2 e2 = *(const float2*)(els + (size_t)(s_l * 3 + head) * 2);
            float t = e2.x + erv;
            t = (t < 0.f) ? 0.2f * t : t;
            w = __expf(t);                 // direct exp: logits bounded
            wS = w * e2.y;                 // fold int8 scale into weight
        }
        denl += w;
        ssrcS[u][l] = s_l;                 // per-wave region: no barrier
        swS[u][l]   = wS;                  // (same-wave lgkmcnt ordering)
        for (int q0 = 0; q0 < cnt; q0 += 8) {
            int sA[8]; float wA[8]; unsigned vA[8];
            #pragma unroll
            for (int b = 0; b < 8; ++b) {
                int e = q0 + b;            // <= 63 always; pads have w=0,s=0
                sA[b] = ssrcS[u][e];
                wA[b] = swS[u][e];
            }
            #pragma unroll
            for (int b = 0; b < 8; ++b)
                vA[b] = *(const unsigned short*)(hseg + (size_t)sA[b] * 384);
            #pragma unroll
            for (int b = 0; b < 8; ++b) {
                int b0 = (int)(signed char)(vA[b] & 0xFF);
                int b1 = (int)(signed char)((vA[b] >> 8) & 0xFF);
                ax += wA[b] * (float)b0;
                ay += wA[b] * (float)b1;
            }
        }
    }

    float den = denl;
    #pragma unroll
    for (int msk = 1; msk < 64; msk <<= 1) den += __shfl_xor(den, msk);
    float r = 1.f / (den + 1e-9f);
    if (deg == 0) r = 0.f;

    if (active) {
        int fb = head * 128 + 2 * l;
        float2 bv = *(const float2*)(bias + fb);
        float vx = ax * r + bv.x; vx = (vx < 0.f) ? 0.01f * vx : vx;
        float vy = ay * r + bv.y; vy = (vy < 0.f) ? 0.01f * vy : vy;
        smS[nl][fb]     = vx;
        smS[nl][fb + 1] = vy;
    }
    __syncthreads();
    if (tid < 128) {
        int mn = tid >> 6;                 // node-local 0/1
        int n2 = blockIdx.x * 2 + mn;
        if (n2 < N) {
            int f0i = (tid & 63) * 2, f1i = f0i + 1;
            float mx = (smS[mn][f0i] + smS[mn][128 + f0i] + smS[mn][256 + f0i]) * (1.0f / 3.0f);
            float my = (smS[mn][f1i] + smS[mn][128 + f1i] + smS[mn][256 + f1i]) * (1.0f / 3.0f);
            short hx = f2bf(mx), hy = f2bf(my);
            unsigned ph = (unsigned)(unsigned short)hx | ((unsigned)(unsigned short)hy << 16);
            *(unsigned*)(outH + (size_t)n2 * 128 + f0i) = ph;
            if (outL) {
                short lx = f2bf(mx - bf2f(hx)), ly = f2bf(my - bf2f(hy));
                unsigned pl = (unsigned)(unsigned short)lx | ((unsigned)(unsigned short)ly << 16);
                *(unsigned*)(outL + (size_t)n2 * 128 + f0i) = pl;
            }
        }
    }
}

// ---------------------------------------------------------------------------
extern "C" void kernel_launch(void* const* d_in, const int* in_sizes, int n_in,
                              void* d_out, int out_size, void* d_ws, size_t ws_size,
                              hipStream_t stream)
{
    const float* in_feat = (const float*)d_in[0];
    const int*   src     = (const int*)d_in[1];
    const int*   dst     = (const int*)d_in[2];
    const float* W1  = (const float*)d_in[3];
    const float* al1 = (const float*)d_in[4];
    const float* ar1 = (const float*)d_in[5];
    const float* b1  = (const float*)d_in[6];
    const float* W2  = (const float*)d_in[7];
    const float* al2 = (const float*)d_in[8];
    const float* ar2 = (const float*)d_in[9];
    const float* b2  = (const float*)d_in[10];
    const float* lw1 = (const float*)d_in[11];
    const float* lb1 = (const float*)d_in[12];
    const float* lw2 = (const float*)d_in[13];
    const float* lb2 = (const float*)d_in[14];
    const float* lw3 = (const float*)d_in[15];
    const float* lb3 = (const float*)d_in[16];
    const float* lw4 = (const float*)d_in[17];
    const float* lb4 = (const float*)d_in[18];
    const float* lw5 = (const float*)d_in[19];
    const float* lb5 = (const float*)d_in[20];

    const int N = in_sizes[0] / 128;   // 50000
    const int E = in_sizes[1];         // 800000

    size_t o = 0;
    auto alloc = [&](size_t bytes) { size_t p = o; o = (o + bytes + 255) & ~(size_t)255; return p; };
    char* ws = (char*)d_ws;
    short* P1h = (short*)(ws + alloc((size_t)N * 128 * 2));
    short* P1l = (short*)(ws + alloc((size_t)N * 128 * 2));
    short* P2h = (short*)(ws + alloc((size_t)N * 128 * 2));
    unsigned char* Aq = (unsigned char*)(ws + alloc((size_t)N * 384));   // int8 gemm out
    float* els1 = (float*)(ws + alloc((size_t)N * 3 * 2 * 4));           // {el1, scale1}
    float* er1  = (float*)(ws + alloc((size_t)N * 3 * 4));
    float* els2 = (float*)(ws + alloc((size_t)N * 3 * 2 * 4));           // {el2, scale2}
    float* er2  = (float*)(ws + alloc((size_t)N * 3 * 4));
    float* u1   = (float*)(ws + alloc((size_t)6 * 128 * 4));
    float* u2   = (float*)(ws + alloc((size_t)6 * 128 * 4));
    int*   cnt  = (int*)(ws + alloc((size_t)N * 4));
    int*   off  = (int*)(ws + alloc((size_t)(N + 1) * 4));
    int*   bsum = (int*)(ws + alloc((size_t)4096));
    int*   csrc = (int*)(ws + alloc((size_t)E * 4));
    short* w1th = (short*)(ws + alloc((size_t)384 * 128 * 2));
    short* w2th = (short*)(ws + alloc((size_t)384 * 128 * 2));
    short* l1th = (short*)(ws + alloc((size_t)128 * 128 * 2));
    short* l1tl = (short*)(ws + alloc((size_t)128 * 128 * 2));
    short* l2th = (short*)(ws + alloc((size_t)128 * 128 * 2));
    short* l2tl = (short*)(ws + alloc((size_t)128 * 128 * 2));
    short* l3th = (short*)(ws + alloc((size_t)128 * 128 * 2));
    short* l3tl = (short*)(ws + alloc((size_t)128 * 128 * 2));
    short* l4th = (short*)(ws + alloc((size_t)128 * 128 * 2));
    short* l4tl = (short*)(ws + alloc((size_t)128 * 128 * 2));
    short* l5th = (short*)(ws + alloc((size_t)6 * 128 * 2));
    short* l5tl = (short*)(ws + alloc((size_t)6 * 128 * 2));
    (void)ws_size;

    float* out = (float*)d_out;

    // ---- fused prep: conv + weight transpose + u-vectors + hist
    hipMemsetAsync(cnt, 0, (size_t)N * 4, stream);
    int n4 = N * 128 / 4;
    int cb = (n4 + 255) / 256;
    int wb = (164608 + 255) / 256;
    int hb = (E + 255) / 256;
    prep_kernel<<<cb + wb + 1 + hb, 256, 0, stream>>>(
        in_feat, P1h, n4, cb, wb, dst, cnt, E,
        W1, W2, lw1, lw2, lw3, lw4, lw5,
        w1th, w2th, l1th, l1tl, l2th, l2tl,
        l3th, l3tl, l4th, l4tl, l5th, l5tl,
        al1, ar1, al2, ar2, u1, u2);

    // ---- CSR scan
    int nb = (N + 1023) / 1024;
    scan_block<<<nb, 1024, 0, stream>>>(cnt, off, bsum, N);
    scan_add2<<<(N + 255) / 256, 256, 0, stream>>>(off, bsum, N, nb);

    int RB = (N + BM - 1) / BM;
    int NG = 3 * RB, NS = 512, NE = 1024;
    int AGB = (N + 1) / 2;

    // ---- L1 mega: gemm1 || scatter || node_el1 (one launch)
    l1_mega<<<NG + NS + NE, 256, 0, stream>>>(
        P1h, w1th, Aq, els1, N, 384, NG,
        src, dst, off, cnt, csrc, E, NS,
        in_feat, u1, er1, N, NE);

    agg_kernel<<<AGB, 384, 0, stream>>>(Aq, els1, er1, off, csrc, b1,
                                        P2h, nullptr, N);

    // ---- GAT layer 2 (gemm + fused exact-u2 logits)
    gemm_l2<<<dim3(3, RB), 256, 0, stream>>>(P2h, w2th, Aq, els2, er2, u2,
                                             N, 384);
    agg_kernel<<<AGB, 384, 0, stream>>>(Aq, els2, er2, off, csrc, b2,
                                        P1h, P1l, N);

    // ---- MLP head (fused lin1..lin5, 64-node blocks)
    int RBM = (N + MROWS - 1) / MROWS;
    mlp_fused<<<RBM, 256, 0, stream>>>(P1h, P1l,
                                       l1th, l1tl, l2th, l2tl, l3th, l3tl,
                                       l4th, l4tl, l5th, l5tl,
                                       lb1, lb2, lb3, lb4, lb5, out, N);
}

// Round 14
// 466.251 us; speedup vs baseline: 1.0959x; 1.0725x over previous
//
#include <hip/hip_runtime.h>
#include <hip/hip_bf16.h>

// ---------------------------------------------------------------------------
// GAT (2 GATConv + 5-layer MLP), MI355X.
// R16: gemm/mlp staging -> global_load_lds(16B) + both-sides XOR swizzle.
// R17-R21: elimination matrix -> agg latency-chain bound. R20 structure
//     (direct exp, batched gathers, barrier-free chunk loop).
// R23 (495.7): int8 rowmax-scaled gather both layers.
// R25/R26/R27 (500.1, absmax 5.72e-6): exact logit decoupling (u = W·a),
//     single-term bf16 gemms, l1_mega (gemm1||scatter||node_el1), u2-logits
//     fused in gemm2 K-loop. Launch count 13 -> 10 (-9 us).
// R28: dual-node waves in agg. Each wave = (head, node-pair): TWO
//     independent latency chains interleaved (csrc/els/h8 of node B issue
//     while node A's serial links resolve). Occupancy preserved
//     (__launch_bounds__(384,8) pins VGPR<=64, 5 blocks/CU; batch depth
//     4/node keeps total in-flight gathers at 8). Per-node arithmetic
//     order identical -> absmax must stay exactly 5.722046e-6.
//     A/B read: agg -> ~75 us = chain-ILP confirmed; agg flat -> agg is
//     outstanding-miss floored (roofline candidate).
// ---------------------------------------------------------------------------

typedef __attribute__((ext_vector_type(8))) short short8;   // 8 bf16 = 4 VGPR
typedef __attribute__((ext_vector_type(4))) float float4v;  // MFMA C/D

__device__ inline short f2bf(float x) {
    union { float f; unsigned u; } v; v.f = x;
    unsigned r = v.u + 0x7FFFu + ((v.u >> 16) & 1u);   // RNE
    return (short)(r >> 16);
}
__device__ inline float bf2f(short b) {
    union { float f; unsigned u; } v;
    v.u = ((unsigned)(unsigned short)b) << 16;
    return v.f;
}
__device__ inline short8 zero8() { short8 z = {0,0,0,0,0,0,0,0}; return z; }

// async global->LDS, 16 B per lane (dest = wave-uniform base + lane*16)
__device__ __forceinline__ void gl_lds16(const short* g, short* l) {
    __builtin_amdgcn_global_load_lds(
        (const __attribute__((address_space(1))) void*)g,
        (__attribute__((address_space(3))) void*)l,
        16, 0, 0);
}

// XOR swizzle for 16B slots within a 64B row (8-way -> 2-way, free per m136).
#define SW(r) ((((r) >> 2) ^ (r)) & 3)

#define BM 128
#define BN 128
#define BK 32
#define MSTR 136   // act row stride in shorts (272 B = 17x16B, breaks pow2)
#define MROWS 64   // mlp_fused rows per block

// ---------------------------------------------------------------------------
// Fused prep: [0,cb) conv (hi only) | [cb,cb+wb) weight transpose |
// [cb+wb] u-vectors (W·a per layer) | rest hist.
__global__ void prep_kernel(
    const float* __restrict__ in_feat, short* __restrict__ P1h,
    int n4, int cb, int wb,
    const int* __restrict__ dst, int* __restrict__ cnt, int E,
    const float* __restrict__ w1, const float* __restrict__ w2,
    const float* __restrict__ m1, const float* __restrict__ m2,
    const float* __restrict__ m3, const float* __restrict__ m4,
    const float* __restrict__ w5,
    short* __restrict__ w1h, short* __restrict__ w2h,
    short* __restrict__ m1h, short* __restrict__ m1l,
    short* __restrict__ m2h, short* __restrict__ m2l,
    short* __restrict__ m3h, short* __restrict__ m3l,
    short* __restrict__ m4h, short* __restrict__ m4l,
    short* __restrict__ w5h, short* __restrict__ w5l,
    const float* __restrict__ al1, const float* __restrict__ ar1,
    const float* __restrict__ al2, const float* __restrict__ ar2,
    float* __restrict__ u1, float* __restrict__ u2)
{
    int blk = blockIdx.x;
    if (blk < cb) {
        int i = blk * 256 + threadIdx.x;
        if (i >= n4) return;
        float4 v = *(const float4*)(in_feat + (size_t)i * 4);
        float xs[4] = {v.x, v.y, v.z, v.w};
        short hs[4];
        #pragma unroll
        for (int j = 0; j < 4; ++j) hs[j] = f2bf(xs[j]);
        *(uint2*)(P1h + (size_t)i * 4) = *(uint2*)hs;
    } else if (blk < cb + wb) {
        int j = (blk - cb) * 256 + threadIdx.x;
        const float* src; short* th; short* tl; int Nc, base;
        if      (j < 49152)  { src = w1; th = w1h; tl = nullptr; Nc = 384; base = 0; }
        else if (j < 98304)  { src = w2; th = w2h; tl = nullptr; Nc = 384; base = 49152; }
        else if (j < 114688) { src = m1; th = m1h; tl = m1l; Nc = 128; base = 98304; }
        else if (j < 131072) { src = m2; th = m2h; tl = m2l; Nc = 128; base = 114688; }
        else if (j < 147456) { src = m3; th = m3h; tl = m3l; Nc = 128; base = 131072; }
        else if (j < 163840) { src = m4; th = m4h; tl = m4l; Nc = 128; base = 147456; }
        else if (j < 164608) { src = w5; th = w5h; tl = w5l; Nc = 6;   base = 163840; }
        else return;
        int i = j - base;
        int k = i / Nc, c = i - k * Nc;
        float v = src[i];
        short h = f2bf(v);
        th[(size_t)c * 128 + k] = h;
        if (tl) tl[(size_t)c * 128 + k] = f2bf(v - bf2f(h));
    } else if (blk == cb + wb) {
        // u-vectors: u[(h*2+s)*128 + k] = sum_f W[k*384 + h*128 + f] * a[h*128+f]
        int t = threadIdx.x;
        const float* W  = (t < 128) ? w1 : w2;
        const float* av = (t < 128) ? al1 : al2;
        const float* rv = (t < 128) ? ar1 : ar2;
        float* u = (t < 128) ? u1 : u2;
        int k = t & 127;
        #pragma unroll
        for (int h = 0; h < 3; ++h) {
            float sl = 0.f, sr = 0.f;
            for (int f = 0; f < 128; ++f) {
                float wv = W[(size_t)k * 384 + h * 128 + f];
                sl += wv * av[h * 128 + f];
                sr += wv * rv[h * 128 + f];
            }
            u[(h * 2 + 0) * 128 + k] = sl;
            u[(h * 2 + 1) * 128 + k] = sr;
        }
    } else {
        int e = (blk - cb - wb - 1) * 256 + threadIdx.x;
        if (e < E) atomicAdd(&cnt[dst[e]], 1);
    }
}

// ---------------------------------------------------------------------------
// GEMM body (device fn): single-term bf16, int8 rowmax quantize.
// LOG=true additionally computes this head's logits el/er = A-row · u
// from the in-register A fragments (u slice preloaded to LDS).
template <bool LOG>
__device__ __forceinline__ void gemm_body(
    const short* __restrict__ Ahi, const short* __restrict__ Bth,
    unsigned char* __restrict__ Cq, float* __restrict__ els,
    float* __restrict__ erv, const float* __restrict__ uvec,
    int M, int Nc, int head, int rby)
{
    __shared__ short Ah[BM * BK], Bh[BN * BK];
    __shared__ float uL[2][128];

    int tid = threadIdx.x, lane = tid & 63, wave = tid >> 6;
    int l15 = lane & 15, q = lane >> 4;
    int rowBase = rby * BM, colBase = head * BN;

    if (LOG) {
        int s = tid >> 7, k = tid & 127;       // 256 threads cover [2][128]
        uL[s][k] = uvec[(head * 2 + s) * 128 + k];
    }

    float4v acc[2][8];
    #pragma unroll
    for (int mt = 0; mt < 2; ++mt)
        #pragma unroll
        for (int nt = 0; nt < 8; ++nt)
            acc[mt][nt] = (float4v){0.f, 0.f, 0.f, 0.f};
    float pl[2] = {0.f, 0.f}, pr[2] = {0.f, 0.f};

    for (int k0 = 0; k0 < 128; k0 += BK) {
        #pragma unroll
        for (int i = 0; i < 2; ++i) {
            int cid = tid + i * 256;             // wave-uniform base + lane
            int r = cid >> 2, sub = cid & 3;
            int gs = (sub ^ SW(r)) * 8;
            gl_lds16(Ahi + (size_t)(rowBase + r) * 128 + k0 + gs, Ah + cid * 8);
            gl_lds16(Bth + (size_t)(colBase + r) * 128 + k0 + gs, Bh + cid * 8);
        }
        __syncthreads();

        short8 aH[2];
        #pragma unroll
        for (int mt = 0; mt < 2; ++mt) {
            int row = wave * 32 + mt * 16 + l15;
            int off = row * 32 + (q ^ SW(row)) * 8;
            aH[mt] = *(short8*)&Ah[off];
        }
        if (LOG) {
            #pragma unroll
            for (int mt = 0; mt < 2; ++mt)
                #pragma unroll
                for (int j = 0; j < 8; ++j) {
                    float av = bf2f(aH[mt][j]);
                    int k = k0 + q * 8 + j;      // lane's global k-slice is q
                    pl[mt] += av * uL[0][k];
                    pr[mt] += av * uL[1][k];
                }
        }
        #pragma unroll
        for (int nt = 0; nt < 8; ++nt) {
            int row = nt * 16 + l15;
            int off = row * 32 + (q ^ SW(row)) * 8;
            short8 bH = *(short8*)&Bh[off];
            #pragma unroll
            for (int mt = 0; mt < 2; ++mt)
                acc[mt][nt] = __builtin_amdgcn_mfma_f32_16x16x32_bf16(aH[mt], bH, acc[mt][nt], 0, 0, 0);
        }
        __syncthreads();
    }

    if (LOG) {
        #pragma unroll
        for (int mt = 0; mt < 2; ++mt) {
            pl[mt] += __shfl_xor(pl[mt], 16);
            pl[mt] += __shfl_xor(pl[mt], 32);
            pr[mt] += __shfl_xor(pr[mt], 16);
            pr[mt] += __shfl_xor(pr[mt], 32);
            int r = rowBase + wave * 32 + mt * 16 + l15;
            if (q == 0 && r < M) {
                els[(size_t)(r * 3 + head) * 2] = pl[mt];
                erv[r * 3 + head] = pr[mt];
            }
        }
    }

    // ---- int8 rowmax quantization: scale = rowmax/127 per (row, head)
    #pragma unroll
    for (int mt = 0; mt < 2; ++mt) {
        #pragma unroll
        for (int i = 0; i < 4; ++i) {
            float rm = 0.f;
            #pragma unroll
            for (int nt = 0; nt < 8; ++nt)
                rm = fmaxf(rm, fabsf(acc[mt][nt][i]));
            #pragma unroll
            for (int mask = 1; mask < 16; mask <<= 1)
                rm = fmaxf(rm, __shfl_xor(rm, mask));
            int r = rowBase + wave * 32 + mt * 16 + q * 4 + i;
            float inv = 127.f / fmaxf(rm, 1e-30f);
            if (l15 == 0 && r < M)
                els[(size_t)(r * 3 + head) * 2 + 1] = rm * (1.f / 127.f);
            #pragma unroll
            for (int nt = 0; nt < 8; ++nt) {
                int c = head * BN + nt * 16 + l15;
                int qi = (int)rintf(acc[mt][nt][i] * inv);
                int qn = __shfl_xor(qi, 1);        // neighbor col c^1
                if (!(l15 & 1) && r < M && c < Nc) {
                    unsigned short pk = (unsigned short)((qi & 0xFF) | ((qn & 0xFF) << 8));
                    *(unsigned short*)(Cq + (size_t)r * Nc + c) = pk;
                }
            }
        }
    }
}

// ---------------------------------------------------------------------------
// L1 mega-launch: [0,NG) gemm1 blocks | [NG,NG+NS) scatter (grid-stride) |
// rest node_el1 (exact fp32 layer-1 logits, grid-stride).
__global__ __launch_bounds__(256) void l1_mega(
    const short* __restrict__ P1h, const short* __restrict__ w1th,
    unsigned char* __restrict__ Cq, float* __restrict__ els1, int M, int Nc,
    int NG,
    const int* __restrict__ src, const int* __restrict__ dst,
    const int* __restrict__ off, int* __restrict__ cnt,
    int* __restrict__ csrc, int E, int NS,
    const float* __restrict__ X, const float* __restrict__ u1,
    float* __restrict__ er1, int N, int NE)
{
    int b = blockIdx.x;
    if (b < NG) {
        gemm_body<false>(P1h, w1th, Cq, els1, nullptr, nullptr,
                         M, Nc, b % 3, b / 3);
        return;
    }
    b -= NG;
    if (b < NS) {
        for (int e = b * 256 + threadIdx.x; e < E; e += NS * 256) {
            int d = dst[e];
            int p = atomicSub(&cnt[d], 1) - 1;
            csrc[off[d] + p] = src[e];
        }
        return;
    }
    b -= NS;
    int wv = threadIdx.x >> 6, l = threadIdx.x & 63;
    for (int n = b * 4 + wv; n < N; n += NE * 4) {
        float2 x = *(const float2*)(X + (size_t)n * 128 + 2 * l);
        float a[6];
        #pragma unroll
        for (int v = 0; v < 6; ++v)
            a[v] = x.x * u1[v * 128 + 2 * l] + x.y * u1[v * 128 + 2 * l + 1];
        #pragma unroll
        for (int msk = 1; msk < 64; msk <<= 1)
            #pragma unroll
            for (int v = 0; v < 6; ++v)
                a[v] += __shfl_xor(a[v], msk);
        if (l == 0) {
            #pragma unroll
            for (int h = 0; h < 3; ++h) {
                els1[(size_t)(n * 3 + h) * 2] = a[h * 2];
                er1[n * 3 + h] = a[h * 2 + 1];
            }
        }
    }
}

// gemm for layer 2: + fused exact-u2 logits from A fragments.
__global__ __launch_bounds__(256) void gemm_l2(
    const short* __restrict__ P2h, const short* __restrict__ w2th,
    unsigned char* __restrict__ Cq, float* __restrict__ els2,
    float* __restrict__ er2, const float* __restrict__ u2, int M, int Nc)
{
    gemm_body<true>(P2h, w2th, Cq, els2, er2, u2, M, Nc,
                    blockIdx.x, blockIdx.y);
}

// ---------------------------------------------------------------------------
// Fused MLP head: 4x (128->128, bias, lrelu) + (128->6, bias) in one kernel.
__global__ __launch_bounds__(256) void mlp_fused(
    const short* __restrict__ Ph, const short* __restrict__ Pl,
    const short* __restrict__ w1h, const short* __restrict__ w1l,
    const short* __restrict__ w2h, const short* __restrict__ w2l,
    const short* __restrict__ w3h, const short* __restrict__ w3l,
    const short* __restrict__ w4h, const short* __restrict__ w4l,
    const short* __restrict__ w5h, const short* __restrict__ w5l,
    const float* __restrict__ b1, const float* __restrict__ b2,
    const float* __restrict__ b3, const float* __restrict__ b4,
    const float* __restrict__ b5,
    float* __restrict__ out, int M)
{
    __shared__ short AH[MROWS * MSTR], AL[MROWS * MSTR];
    __shared__ short WH[128 * BK], WL[128 * BK];

    int tid = threadIdx.x, lane = tid & 63, wave = tid >> 6;
    int l15 = lane & 15, q = lane >> 4;
    int rowBase = blockIdx.x * MROWS;

    #pragma unroll
    for (int s = 0; s < 4; ++s) {
        int idx = tid + s * 256;
        int r = idx >> 4, kq = (idx & 15) * 8;
        int gr = rowBase + r;
        short8 vh = zero8(), vl = zero8();
        if (gr < M) {
            vh = *(const short8*)(Ph + (size_t)gr * 128 + kq);
            vl = *(const short8*)(Pl + (size_t)gr * 128 + kq);
        }
        *(short8*)&AH[r * MSTR + kq] = vh;
        *(short8*)&AL[r * MSTR + kq] = vl;
    }

    const short* Whs[4] = {w1h, w2h, w3h, w4h};
    const short* Wls[4] = {w1l, w2l, w3l, w4l};
    const float* Bss[4] = {b1, b2, b3, b4};

    #pragma unroll
    for (int L = 0; L < 4; ++L) {
        float4v acc[8];
        #pragma unroll
        for (int nt = 0; nt < 8; ++nt)
            acc[nt] = (float4v){0.f, 0.f, 0.f, 0.f};

        for (int k0 = 0; k0 < 128; k0 += BK) {
            #pragma unroll
            for (int i = 0; i < 4; ++i) {          // i<2: hi plane, i>=2: lo
                int c2 = tid + (i & 1) * 256;       // 0..511
                int r = c2 >> 2, sub = c2 & 3;
                int gs = (sub ^ SW(r)) * 8;
                if (i < 2) gl_lds16(Whs[L] + (size_t)r * 128 + k0 + gs, WH + c2 * 8);
                else       gl_lds16(Wls[L] + (size_t)r * 128 + k0 + gs, WL + c2 * 8);
            }
            __syncthreads();
            int offa = (wave * 16 + l15) * MSTR + k0 + q * 8;
            short8 aH  = *(short8*)&AH[offa];
            short8 aL2 = *(short8*)&AL[offa];
            #pragma unroll
            for (int nt = 0; nt < 8; ++nt) {
                int row = nt * 16 + l15;
                int off = row * 32 + (q ^ SW(row)) * 8;
                short8 bH = *(short8*)&WH[off];
                short8 bL = *(short8*)&WL[off];
                acc[nt] = __builtin_amdgcn_mfma_f32_16x16x32_bf16(aH, bH, acc[nt], 0, 0, 0);
                acc[nt] = __builtin_amdgcn_mfma_f32_16x16x32_bf16(aH, bL, acc[nt], 0, 0, 0);
                acc[nt] = __builtin_amdgcn_mfma_f32_16x16x32_bf16(aL2, bH, acc[nt], 0, 0, 0);
            }
            __syncthreads();
        }
        #pragma unroll
        for (int nt = 0; nt < 8; ++nt) {
            int c = nt * 16 + l15;
            float bv = Bss[L][c];
            #pragma unroll
            for (int i = 0; i < 4; ++i) {
                int r = wave * 16 + q * 4 + i;
                float v = acc[nt][i] + bv;
                v = (v < 0.f) ? 0.01f * v : v;
                short hh = f2bf(v);
                AH[r * MSTR + c] = hh;
                AL[r * MSTR + c] = f2bf(v - bf2f(hh));
            }
        }
        __syncthreads();
    }

    float4v acc5 = (float4v){0.f, 0.f, 0.f, 0.f};
    for (int k0 = 0; k0 < 128; k0 += BK) {
        if (tid < 128) {
            int plane = tid >> 6, rem = tid & 63;
            int c = rem >> 2, sub = rem & 3;
            short8 v = zero8();
            if (c < 6)
                v = *(const short8*)((plane ? w5l : w5h) + (size_t)c * 128 + k0 + sub * 8);
            *(short8*)&((plane ? WL : WH)[c * 32 + (sub ^ SW(c)) * 8]) = v;
        }
        __syncthreads();
        int offa = (wave * 16 + l15) * MSTR + k0 + q * 8;
        short8 aH  = *(short8*)&AH[offa];
        short8 aL2 = *(short8*)&AL[offa];
        int offb = l15 * 32 + (q ^ SW(l15)) * 8;
        short8 bH = *(short8*)&WH[offb];
        short8 bL = *(short8*)&WL[offb];
        acc5 = __builtin_amdgcn_mfma_f32_16x16x32_bf16(aH, bH, acc5, 0, 0, 0);
        acc5 = __builtin_amdgcn_mfma_f32_16x16x32_bf16(aH, bL, acc5, 0, 0, 0);
        acc5 = __builtin_amdgcn_mfma_f32_16x16x32_bf16(aL2, bH, acc5, 0, 0, 0);
        __syncthreads();
    }
    if (l15 < 6) {
        float bv = b5[l15];
        #pragma unroll
        for (int i = 0; i < 4; ++i) {
            int r = rowBase + wave * 16 + q * 4 + i;
            if (r < M) out[(size_t)r * 6 + l15] = acc5[i] + bv;
        }
    }
}

// ---------------------------------------------------------------------------
// CSR build (hist lives in prep_kernel)
__global__ __launch_bounds__(1024) void scan_block(const int* __restrict__ cnt,
                                                   int* __restrict__ off,
                                                   int* __restrict__ bsum, int n)
{
    __shared__ int tmp[1024];
    int tid = threadIdx.x;
    int i = blockIdx.x * 1024 + tid;
    int v = (i < n) ? cnt[i] : 0;
    tmp[tid] = v;
    __syncthreads();
    for (int s = 1; s < 1024; s <<= 1) {
        int t = (tid >= s) ? tmp[tid - s] : 0;
        __syncthreads();
        tmp[tid] += t;
        __syncthreads();
    }
    if (i < n) off[i] = tmp[tid] - v;
    if (tid == 1023) bsum[blockIdx.x] = tmp[1023];
}

__global__ void scan_add2(int* __restrict__ off, const int* __restrict__ bsum,
                          int n, int nb)
{
    __shared__ int pre[64];
    int tid = threadIdx.x;
    if (tid < 64) {
        int v = (tid < nb) ? bsum[tid] : 0;
        #pragma unroll
        for (int s = 1; s < 64; s <<= 1) {
            int t = __shfl_up(v, s);
            if (tid >= s) v += t;
        }
        pre[tid] = v;
    }
    __syncthreads();
    int i = blockIdx.x * blockDim.x + tid;
    if (i < n) {
        int chunk = i >> 10;
        off[i] += chunk ? pre[chunk - 1] : 0;
    }
    if (i == 0) off[n] = pre[nb - 1];
}

// ---------------------------------------------------------------------------
// Fused edge-softmax + weighted gather + bias + lrelu + head-mean.
// R28: 4 nodes/block, 384 thr; wave u = (head = u%3, node-pair = u/3).
// Each wave interleaves TWO independent per-node chains (csrc -> els ->
// int8 gather), 4-deep batching per node (8 gathers in flight total).
// Per-node arithmetic order identical to R23/R27 -> bit-exact output.
__global__ __launch_bounds__(384, 8) void agg_kernel(
    const unsigned char* __restrict__ h8, const float* __restrict__ els,
    const float* __restrict__ er, const int* __restrict__ off,
    const int* __restrict__ csrc, const float* __restrict__ bias,
    short* __restrict__ outH, short* __restrict__ outL, int N)
{
    int tid = threadIdx.x;         // 0..383
    int u = tid >> 6;              // wave 0..5
    int np = u / 3;                // node-pair 0/1
    int head = u - np * 3;         // 0..2
    int l = tid & 63;
    int nA = blockIdx.x * 4 + np * 2;
    int nB = nA + 1;
    bool aA = (nA < N), aB = (nB < N);

    __shared__ int   ssrcS[6][2][64];
    __shared__ float swS[6][2][64];
    __shared__ float smS[4][384];

    int begA = 0, degA = 0, begB = 0, degB = 0;
    float ervA = 0.f, ervB = 0.f;
    if (aA) { begA = off[nA]; degA = off[nA + 1] - begA; ervA = er[nA * 3 + head]; }
    if (aB) { begB = off[nB]; degB = off[nB + 1] - begB; ervB = er[nB * 3 + head]; }

    const unsigned char* hseg = h8 + head * 128 + l * 2;
    float axA = 0.f, ayA = 0.f, dA = 0.f;
    float axB = 0.f, ayB = 0.f, dB = 0.f;
    int mdeg = max(degA, degB);

    for (int base = 0; base < mdeg; base += 64) {
        int cntA = min(64, max(0, degA - base));
        int cntB = min(64, max(0, degB - base));
        int sA = 0, sB = 0;
        float wA = 0.f, wSA = 0.f, wB = 0.f, wSB = 0.f;
        if (l < cntA) sA = csrc[begA + base + l];      // independent issues
        if (l < cntB) sB = csrc[begB + base + l];
        if (l < cntA) {
            float2 e2 = *(const float2*)(els + (size_t)(sA * 3 + head) * 2);
            float t = e2.x + ervA;
            t = (t < 0.f) ? 0.2f * t : t;
            wA = __expf(t); wSA = wA * e2.y;
        }
        if (l < cntB) {
            float2 e2 = *(const float2*)(els + (size_t)(sB * 3 + head) * 2);
            float t = e2.x + ervB;
            t = (t < 0.f) ? 0.2f * t : t;
            wB = __expf(t); wSB = wB * e2.y;
        }
        dA += wA; dB += wB;
        ssrcS[u][0][l] = sA;  swS[u][0][l] = wSA;      // per-wave: no barrier
        ssrcS[u][1][l] = sB;  swS[u][1][l] = wSB;
        int cmax = max(cntA, cntB);
        for (int q0 = 0; q0 < cmax; q0 += 4) {         // 4/node = 8 in flight
            int sa[4], sb[4]; float wa[4], wb[4]; unsigned va[4], vb[4];
            #pragma unroll
            for (int b = 0; b < 4; ++b) {
                int e = q0 + b;                        // <= 63; pads w=0,s=0
                sa[b] = ssrcS[u][0][e]; wa[b] = swS[u][0][e];
                sb[b] = ssrcS[u][1][e]; wb[b] = swS[u][1][e];
            }
            #pragma unroll
            for (int b = 0; b < 4; ++b) {
                va[b] = *(const unsigned short*)(hseg + (size_t)sa[b] * 384);
                vb[b] = *(const unsigned short*)(hseg + (size_t)sb[b] * 384);
            }
            #pragma unroll
            for (int b = 0; b < 4; ++b) {
                axA += wa[b] * (float)(int)(signed char)(va[b] & 0xFF);
                ayA += wa[b] * (float)(int)(signed char)((va[b] >> 8) & 0xFF);
                axB += wb[b] * (float)(int)(signed char)(vb[b] & 0xFF);
                ayB += wb[b] * (float)(int)(signed char)((vb[b] >> 8) & 0xFF);
            }
        }
    }

    #pragma unroll
    for (int msk = 1; msk < 64; msk <<= 1) {
        dA += __shfl_xor(dA, msk);
        dB += __shfl_xor(dB, msk);
    }
    float rA = 1.f / (dA + 1e-9f); if (degA == 0) rA = 0.f;
    float rB = 1.f / (dB + 1e-9f); if (degB == 0) rB = 0.f;

    int fb = head * 128 + 2 * l;
    float2 bv = *(const float2*)(bias + fb);
    if (aA) {
        float vx = axA * rA + bv.x; vx = (vx < 0.f) ? 0.01f * vx : vx;
        float vy = ayA * rA + bv.y; vy = (vy < 0.f) ? 0.01f * vy : vy;
        smS[np * 2 + 0][fb]     = vx;
        smS[np * 2 + 0][fb + 1] = vy;
    }
    if (aB) {
        float vx = axB * rB + bv.x; vx = (vx < 0.f) ? 0.01f * vx : vx;
        float vy = ayB * rB + bv.y; vy = (vy < 0.f) ? 0.01f * vy : vy;
        smS[np * 2 + 1][fb]     = vx;
        smS[np * 2 + 1][fb + 1] = vy;
    }
    __syncthreads();
    if (tid < 256) {
        int mn = tid >> 6;                 // node-local 0..3
        int n2 = blockIdx.x * 4 + mn;
        if (n2 < N) {
            int f0i = (tid & 63) * 2, f1i = f0i + 1;
            float mx = (smS[mn][f0i] + smS[mn][128 + f0i] + smS[mn][256 + f0i]) * (1.0f / 3.0f);
            float my = (smS[mn][f1i] + smS[mn][128 + f1i] + smS[mn][256 + f1i]) * (1.0f / 3.0f);
            short hx = f2bf(mx), hy = f2bf(my);
            unsigned ph = (unsigned)(unsigned short)hx | ((unsigned)(unsigned short)hy << 16);
            *(unsigned*)(outH + (size_t)n2 * 128 + f0i) = ph;
            if (outL) {
                short lx = f2bf(mx - bf2f(hx)), ly = f2bf(my - bf2f(hy));
                unsigned pl = (unsigned)(unsigned short)lx | ((unsigned)(unsigned short)ly << 16);
                *(unsigned*)(outL + (size_t)n2 * 128 + f0i) = pl;
            }
        }
    }
}

// ---------------------------------------------------------------------------
extern "C" void kernel_launch(void* const* d_in, const int* in_sizes, int n_in,
                              void* d_out, int out_size, void* d_ws, size_t ws_size,
                              hipStream_t stream)
{
    const float* in_feat = (const float*)d_in[0];
    const int*   src     = (const int*)d_in[1];
    const int*   dst     = (const int*)d_in[2];
    const float* W1  = (const float*)d_in[3];
    const float* al1 = (const float*)d_in[4];
    const float* ar1 = (const float*)d_in[5];
    const float* b1  = (const float*)d_in[6];
    const float* W2  = (const float*)d_in[7];
    const float* al2 = (const float*)d_in[8];
    const float* ar2 = (const float*)d_in[9];
    const float* b2  = (const float*)d_in[10];
    const float* lw1 = (const float*)d_in[11];
    const float* lb1 = (const float*)d_in[12];
    const float* lw2 = (const float*)d_in[13];
    const float* lb2 = (const float*)d_in[14];
    const float* lw3 = (const float*)d_in[15];
    const float* lb3 = (const float*)d_in[16];
    const float* lw4 = (const float*)d_in[17];
    const float* lb4 = (const float*)d_in[18];
    const float* lw5 = (const float*)d_in[19];
    const float* lb5 = (const float*)d_in[20];

    const int N = in_sizes[0] / 128;   // 50000
    const int E = in_sizes[1];         // 800000

    size_t o = 0;
    auto alloc = [&](size_t bytes) { size_t p = o; o = (o + bytes + 255) & ~(size_t)255; return p; };
    char* ws = (char*)d_ws;
    short* P1h = (short*)(ws + alloc((size_t)N * 128 * 2));
    short* P1l = (short*)(ws + alloc((size_t)N * 128 * 2));
    short* P2h = (short*)(ws + alloc((size_t)N * 128 * 2));
    unsigned char* Aq = (unsigned char*)(ws + alloc((size_t)N * 384));   // int8 gemm out
    float* els1 = (float*)(ws + alloc((size_t)N * 3 * 2 * 4));           // {el1, scale1}
    float* er1  = (float*)(ws + alloc((size_t)N * 3 * 4));
    float* els2 = (float*)(ws + alloc((size_t)N * 3 * 2 * 4));           // {el2, scale2}
    float* er2  = (float*)(ws + alloc((size_t)N * 3 * 4));
    float* u1   = (float*)(ws + alloc((size_t)6 * 128 * 4));
    float* u2   = (float*)(ws + alloc((size_t)6 * 128 * 4));
    int*   cnt  = (int*)(ws + alloc((size_t)N * 4));
    int*   off  = (int*)(ws + alloc((size_t)(N + 1) * 4));
    int*   bsum = (int*)(ws + alloc((size_t)4096));
    int*   csrc = (int*)(ws + alloc((size_t)E * 4));
    short* w1th = (short*)(ws + alloc((size_t)384 * 128 * 2));
    short* w2th = (short*)(ws + alloc((size_t)384 * 128 * 2));
    short* l1th = (short*)(ws + alloc((size_t)128 * 128 * 2));
    short* l1tl = (short*)(ws + alloc((size_t)128 * 128 * 2));
    short* l2th = (short*)(ws + alloc((size_t)128 * 128 * 2));
    short* l2tl = (short*)(ws + alloc((size_t)128 * 128 * 2));
    short* l3th = (short*)(ws + alloc((size_t)128 * 128 * 2));
    short* l3tl = (short*)(ws + alloc((size_t)128 * 128 * 2));
    short* l4th = (short*)(ws + alloc((size_t)128 * 128 * 2));
    short* l4tl = (short*)(ws + alloc((size_t)128 * 128 * 2));
    short* l5th = (short*)(ws + alloc((size_t)6 * 128 * 2));
    short* l5tl = (short*)(ws + alloc((size_t)6 * 128 * 2));
    (void)ws_size;

    float* out = (float*)d_out;

    // ---- fused prep: conv + weight transpose + u-vectors + hist
    hipMemsetAsync(cnt, 0, (size_t)N * 4, stream);
    int n4 = N * 128 / 4;
    int cb = (n4 + 255) / 256;
    int wb = (164608 + 255) / 256;
    int hb = (E + 255) / 256;
    prep_kernel<<<cb + wb + 1 + hb, 256, 0, stream>>>(
        in_feat, P1h, n4, cb, wb, dst, cnt, E,
        W1, W2, lw1, lw2, lw3, lw4, lw5,
        w1th, w2th, l1th, l1tl, l2th, l2tl,
        l3th, l3tl, l4th, l4tl, l5th, l5tl,
        al1, ar1, al2, ar2, u1, u2);

    // ---- CSR scan
    int nb = (N + 1023) / 1024;
    scan_block<<<nb, 1024, 0, stream>>>(cnt, off, bsum, N);
    scan_add2<<<(N + 255) / 256, 256, 0, stream>>>(off, bsum, N, nb);

    int RB = (N + BM - 1) / BM;
    int NG = 3 * RB, NS = 512, NE = 1024;
    int AGB = (N + 3) / 4;

    // ---- L1 mega: gemm1 || scatter || node_el1 (one launch)
    l1_mega<<<NG + NS + NE, 256, 0, stream>>>(
        P1h, w1th, Aq, els1, N, 384, NG,
        src, dst, off, cnt, csrc, E, NS,
        in_feat, u1, er1, N, NE);

    agg_kernel<<<AGB, 384, 0, stream>>>(Aq, els1, er1, off, csrc, b1,
                                        P2h, nullptr, N);

    // ---- GAT layer 2 (gemm + fused exact-u2 logits)
    gemm_l2<<<dim3(3, RB), 256, 0, stream>>>(P2h, w2th, Aq, els2, er2, u2,
                                             N, 384);
    agg_kernel<<<AGB, 384, 0, stream>>>(Aq, els2, er2, off, csrc, b2,
                                        P1h, P1l, N);

    // ---- MLP head (fused lin1..lin5, 64-node blocks)
    int RBM = (N + MROWS - 1) / MROWS;
    mlp_fused<<<RBM, 256, 0, stream>>>(P1h, P1l,
                                       l1th, l1tl, l2th, l2tl, l3th, l3tl,
                                       l4th, l4tl, l5th, l5tl,
                                       lb1, lb2, lb3, lb4, lb5, out, N);
}